// Round 8
// baseline (601.534 us; speedup 1.0000x reference)
//
#include <hip/hip_runtime.h>
#include <hip/hip_bf16.h>
#include <math.h>

// Problem constants (B,T,E)=(4,2048,512), H=8, D=64, HID=H*E=4096.
#define Bsz 4
#define Tt 2048
#define Ee 512
#define Hh 8
#define Dd 64
#define HIDs 4096
#define Mrows (Bsz * Tt)   // 8192 token rows

typedef __attribute__((ext_vector_type(8))) short short8;   // 8 bf16 (4 VGPRs)
typedef __attribute__((ext_vector_type(4))) float f32x4;    // MFMA accumulator

#define AS1 __attribute__((address_space(1)))
#define AS3 __attribute__((address_space(3)))

__device__ __forceinline__ unsigned short f2bfu(float f) {   // RNE float->bf16 bits
    unsigned u = __float_as_uint(f);
    return (unsigned short)((u + 0x7fffu + ((u >> 16) & 1u)) >> 16);
}
__device__ __forceinline__ unsigned scale2(unsigned w, float s) {  // 2xbf16 *= s
    float lo = __uint_as_float(w << 16) * s;
    float hi = __uint_as_float(w & 0xffff0000u) * s;
    return (unsigned)f2bfu(lo) | ((unsigned)f2bfu(hi) << 16);
}

// ---------------------------------------------------------------------------
// LayerNorm: one 256-thread block per row of 512.
// out_f = LN(x)*g+b + addb[col]  (fp32; addb folds the NEXT stage's bias)
// out_bf = LN(x)*g+b             (bf16 GEMM operand, no addb)
__global__ __launch_bounds__(256) void ln_kernel(const float* __restrict__ x,
        const float* __restrict__ g, const float* __restrict__ b,
        const float* __restrict__ addb,
        float* __restrict__ out_f, __hip_bfloat16* __restrict__ out_bf) {
    int row = blockIdx.x;
    int tid = threadIdx.x;
    const float* xr = x + (size_t)row * Ee;
    float v0 = xr[tid];
    float v1 = xr[tid + 256];
    float s = v0 + v1;
    float sq = v0 * v0 + v1 * v1;
#pragma unroll
    for (int off = 32; off > 0; off >>= 1) {
        s  += __shfl_xor(s, off, 64);
        sq += __shfl_xor(sq, off, 64);
    }
    __shared__ float ls[4], lq[4];
    int wid = tid >> 6, lane = tid & 63;
    if (lane == 0) { ls[wid] = s; lq[wid] = sq; }
    __syncthreads();
    s  = ls[0] + ls[1] + ls[2] + ls[3];
    sq = lq[0] + lq[1] + lq[2] + lq[3];
    float mean = s * (1.0f / Ee);
    float var  = sq * (1.0f / Ee) - mean * mean;   // biased var, like jnp.var
    float rstd = rsqrtf(var + 1e-5f);
    float o0 = (v0 - mean) * rstd * g[tid]       + b[tid];
    float o1 = (v1 - mean) * rstd * g[tid + 256] + b[tid + 256];
    float* orow = out_f + (size_t)row * Ee;
    orow[tid]       = o0 + addb[tid];
    orow[tid + 256] = o1 + addb[tid + 256];
    __hip_bfloat16* brow = out_bf + (size_t)row * Ee;
    brow[tid]       = __float2bfloat16(o0);
    brow[tid + 256] = __float2bfloat16(o1);
}

// ---------------------------------------------------------------------------
// Generic fp32 [R][C] -> bf16 [C][R] transpose, 64x64 LDS tiles.
__global__ __launch_bounds__(256) void transpose_bf16(const float* __restrict__ in,
        __hip_bfloat16* __restrict__ outp, int R, int C) {
    __shared__ float tile[64][65];
    int c0 = blockIdx.x * 64, r0 = blockIdx.y * 64;
    int tc = threadIdx.x & 63, tg = threadIdx.x >> 6;
#pragma unroll
    for (int i = 0; i < 16; ++i) {
        int r = tg * 16 + i;
        tile[r][tc] = in[(size_t)(r0 + r) * C + c0 + tc];
    }
    __syncthreads();
#pragma unroll
    for (int i = 0; i < 16; ++i) {
        int cc = tg * 16 + i;
        outp[(size_t)(c0 + cc) * R + r0 + tc] = __float2bfloat16(tile[tc][cc]);
    }
}

// ---------------------------------------------------------------------------
// Repack Wq/Wk/Wv [H,E,D] fp32 -> bqT [3*H*D][E] bf16 (row c=p*512+h*64+d).
__global__ __launch_bounds__(256) void repack_qkv_t(const float* __restrict__ Wq,
        const float* __restrict__ Wk, const float* __restrict__ Wv,
        __hip_bfloat16* __restrict__ bqT) {
    int blk = blockIdx.x;            // p*64 + h*8 + et
    int p = blk >> 6, h = (blk >> 3) & 7, et = blk & 7;
    const float* W = (p == 0) ? Wq : ((p == 1) ? Wk : Wv);
    __shared__ float tile[64][65];
    int td = threadIdx.x & 63, tg = threadIdx.x >> 6;
#pragma unroll
    for (int i = 0; i < 16; ++i) {
        int e = tg * 16 + i;
        tile[e][td] = W[((size_t)h * Ee + et * 64 + e) * Dd + td];
    }
    __syncthreads();
#pragma unroll
    for (int i = 0; i < 16; ++i) {
        int d = tg * 16 + i;
        bqT[((size_t)(p * 512 + h * 64 + d)) * Ee + et * 64 + td] = __float2bfloat16(tile[td][d]);
    }
}

// ---------------------------------------------------------------------------
// bf16 MFMA GEMM: 128x128 tile, BK=64 as two 32-wide k-panels,
// global_load_lds width 16. 1D grid with XCD-aware swizzle. Split-K via
// virtual z. Modes: 0: Cb = bf16(acc); 4: atomicAdd(Cf[ci], acc).
__global__ __launch_bounds__(256) void mfma_gemm(
        const __hip_bfloat16* __restrict__ A, int lda,
        const __hip_bfloat16* __restrict__ B, int ldb,
        float* __restrict__ Cf, __hip_bfloat16* __restrict__ Cb, int ldc, int Kc,
        int mode, int nx, int ny) {
    __shared__ __hip_bfloat16 As[2 * 128 * 32];   // [panel][m][k32]
    __shared__ __hip_bfloat16 Bs[2 * 128 * 32];   // [panel][n][k32]
    int tid = threadIdx.x;
    int lane = tid & 63, wave = tid >> 6;
    int wm = wave >> 1, wn = wave & 1;
    int L = blockIdx.x;
    int slots = (int)gridDim.x >> 3;
    int v = (L & 7) * slots + (L >> 3);
    int bx = v % nx;
    int rem = v / nx;
    int by = rem % ny;
    int bz = rem / ny;
    int row0 = by * 128, col0 = bx * 128;
    int kbase = bz * Kc;
    f32x4 acc[4][4];
#pragma unroll
    for (int i = 0; i < 4; ++i)
#pragma unroll
        for (int j = 0; j < 4; ++j) acc[i][j] = (f32x4){0.f, 0.f, 0.f, 0.f};

    int fr = lane & 15;
    int kq = (lane >> 4) << 3;            // fragment k-offset: 0/8/16/24

    for (int k0 = kbase; k0 < kbase + Kc; k0 += 64) {
        __syncthreads();
#pragma unroll
        for (int j = 0; j < 4; ++j) {
            int c  = j * 256 + tid;
            int cb = j * 256 + wave * 64;         // wave-uniform base chunk
            int p  = c >> 9, cp = c & 511;
            int r  = cp >> 2, kg = (cp & 3) << 3;
            int ko = k0 + p * 32 + kg;
            __builtin_amdgcn_global_load_lds(
                (const AS1 void*)(A + (size_t)(row0 + r) * lda + ko),
                (AS3 void*)(As + cb * 8), 16, 0, 0);
            __builtin_amdgcn_global_load_lds(
                (const AS1 void*)(B + (size_t)(col0 + r) * ldb + ko),
                (AS3 void*)(Bs + cb * 8), 16, 0, 0);
        }
        __syncthreads();
#pragma unroll
        for (int ks = 0; ks < 2; ++ks) {
            short8 afr[4], bfr[4];
#pragma unroll
            for (int i = 0; i < 4; ++i) {
                afr[i] = *(const short8*)(As + ks * 4096 + (wm * 64 + i * 16 + fr) * 32 + kq);
                bfr[i] = *(const short8*)(Bs + ks * 4096 + (wn * 64 + i * 16 + fr) * 32 + kq);
            }
#pragma unroll
            for (int i = 0; i < 4; ++i)
#pragma unroll
                for (int j = 0; j < 4; ++j)
                    acc[i][j] = __builtin_amdgcn_mfma_f32_16x16x32_bf16(afr[i], bfr[j], acc[i][j], 0, 0, 0);
        }
    }
    int rq = (lane >> 4) << 2;
#pragma unroll
    for (int i = 0; i < 4; ++i) {
#pragma unroll
        for (int j = 0; j < 4; ++j) {
#pragma unroll
            for (int gidx = 0; gidx < 4; ++gidx) {
                int r = row0 + wm * 64 + i * 16 + rq + gidx;
                int c = col0 + wn * 64 + j * 16 + fr;
                size_t ci = (size_t)r * ldc + c;
                float val = acc[i][j][gidx];
                if (mode == 0) {
                    Cb[ci] = __float2bfloat16(val);
                } else {
                    atomicAdd(Cf + ci, val);
                }
            }
        }
    }
}

// ---------------------------------------------------------------------------
// Fused FFN: out += relu(xn2 @ W1 + b1) @ W2, block owns 32 rows exclusively.
// Grid 256 x 256 threads (4 waves). X rows staged once in LDS (k-panels);
// weights streamed as B-fragments directly from global (L2-shared across the
// XCD's blocks) -- no LDS staging, no atomics, h never touches HBM.
// Per hid-chunk of 64: GEMM1 (wave w -> hid cols w*16..w*16+15, K=512),
// h -> LDS (C-layout -> A-frag round-trip), GEMM2 (wave w -> out cols
// w*128..w*128+127, K=64), register out-accumulate [2m][8n] f32x4.
__global__ __launch_bounds__(256) void ffn_fused(
        const __hip_bfloat16* __restrict__ X,    // xn2 bf16 [8192][512]
        const __hip_bfloat16* __restrict__ w1T,  // [4096][512]
        const __hip_bfloat16* __restrict__ w2T,  // [512][4096]
        const float* __restrict__ b1,            // [4096]
        float* __restrict__ out) {               // [8192][512], base = xn2+b2
    __shared__ __hip_bfloat16 Xs[16 * 32 * 32];  // [k-panel][m][32] = 32 KB
    __shared__ __hip_bfloat16 hS[32 * 64];       // h chunk [m][64] = 4 KB
    int tid = threadIdx.x;
    int lane = tid & 63, wave = tid >> 6;
    int g = lane >> 4, c = lane & 15;
    int row0 = blockIdx.x * 32;

    // stage X rows into k-panels: chunk cid -> (p = cid>>7, r = (cid>>2)&31,
    // kg = cid&3); LDS elem offset = cid*8.
#pragma unroll
    for (int j = 0; j < 8; ++j) {
        int cid = j * 256 + tid;
        int cb  = j * 256 + wave * 64;
        int p = cid >> 7, r = (cid >> 2) & 31, kg = cid & 3;
        __builtin_amdgcn_global_load_lds(
            (const AS1 void*)(X + (size_t)(row0 + r) * 512 + p * 32 + kg * 8),
            (AS3 void*)(Xs + cb * 8), 16, 0, 0);
    }

    f32x4 oacc[2][8];
#pragma unroll
    for (int i = 0; i < 2; ++i)
#pragma unroll
        for (int j = 0; j < 8; ++j) oacc[i][j] = (f32x4){0.f, 0.f, 0.f, 0.f};
    __syncthreads();

    unsigned short* hS16 = (unsigned short*)hS;
    for (int ch = 0; ch < 64; ++ch) {
        int hid0 = ch * 64;
        // ---- GEMM1: h[2 m-tiles][16 cols] for this wave's hid group
        f32x4 hacc[2];
        hacc[0] = (f32x4){0.f, 0.f, 0.f, 0.f};
        hacc[1] = (f32x4){0.f, 0.f, 0.f, 0.f};
        const __hip_bfloat16* w1p =
            w1T + (size_t)(hid0 + wave * 16 + c) * 512 + g * 8;
#pragma unroll
        for (int ks = 0; ks < 16; ++ks) {
            short8 bf = *(const short8*)(w1p + ks * 32);
            short8 a0 = *(const short8*)(Xs + ks * 1024 + c * 32 + g * 8);
            short8 a1 = *(const short8*)(Xs + ks * 1024 + (16 + c) * 32 + g * 8);
            hacc[0] = __builtin_amdgcn_mfma_f32_16x16x32_bf16(a0, bf, hacc[0], 0, 0, 0);
            hacc[1] = __builtin_amdgcn_mfma_f32_16x16x32_bf16(a1, bf, hacc[1], 0, 0, 0);
        }
        // bias + relu -> hS (C layout: row = g*4+r, col = c)
        float bv = b1[hid0 + wave * 16 + c];
#pragma unroll
        for (int i = 0; i < 2; ++i)
#pragma unroll
            for (int r = 0; r < 4; ++r) {
                float t = hacc[i][r] + bv;
                hS16[(i * 16 + g * 4 + r) * 64 + wave * 16 + c] =
                    f2bfu(t > 0.f ? t : 0.f);
            }
        __syncthreads();
        // ---- GEMM2: oacc += h @ W2-chunk (A from hS, B from global)
#pragma unroll
        for (int ks = 0; ks < 2; ++ks) {
            short8 a0 = *(const short8*)(hS + c * 64 + ks * 32 + g * 8);
            short8 a1 = *(const short8*)(hS + (16 + c) * 64 + ks * 32 + g * 8);
#pragma unroll
            for (int j = 0; j < 8; ++j) {
                short8 bf = *(const short8*)(w2T +
                    (size_t)(wave * 128 + j * 16 + c) * 4096 + hid0 + ks * 32 + g * 8);
                oacc[0][j] = __builtin_amdgcn_mfma_f32_16x16x32_bf16(a0, bf, oacc[0][j], 0, 0, 0);
                oacc[1][j] = __builtin_amdgcn_mfma_f32_16x16x32_bf16(a1, bf, oacc[1][j], 0, 0, 0);
            }
        }
        __syncthreads();
    }
    // ---- epilogue: out[row][col] += oacc (rows exclusive -> plain RMW)
#pragma unroll
    for (int i = 0; i < 2; ++i)
#pragma unroll
        for (int j = 0; j < 8; ++j)
#pragma unroll
            for (int r = 0; r < 4; ++r) {
                int row = row0 + i * 16 + g * 4 + r;
                int col = wave * 128 + j * 16 + c;
                out[(size_t)row * 512 + col] += oacc[i][j][r];
            }
}

// ---------------------------------------------------------------------------
// MFMA flash attention, no-max softmax. One block = 128 Q rows of one (b,h);
// 8 waves x 16 rows. Scores are bounded (LN-scale inputs, T^-0.5 scale), so
// exp2 without max subtraction is safe -> no cross-lane reductions at all.
// Row-sum l accumulated on the matrix pipe via a B=ones MFMA.
__global__ __launch_bounds__(512) void attn_mfma(const __hip_bfloat16* __restrict__ qkvb,
        __hip_bfloat16* __restrict__ ob) {
    __shared__ __hip_bfloat16 KsS[64 * 72];     // K tile [s][d], pad 72
    __shared__ __hip_bfloat16 VtS[64 * 72];     // V^T tile [d][s], pad 72
    __shared__ __hip_bfloat16 PsS[8 * 16 * 72]; // P [wave][q][s] bf16; Q overlays
    __hip_bfloat16* Qs = PsS;                   // Q staging [128 q][72]

    const unsigned short* q16 = (const unsigned short*)qkvb;
    int tid  = threadIdx.x;
    int lane = tid & 63, wave = tid >> 6;
    int g = lane >> 4, c = lane & 15;
    int blk = blockIdx.x;
    int qb  = 15 - (blk >> 5);                // global heavy-first
    int bh  = blk & 31;
    int b = bh >> 3, h = bh & 7;
    int base = qb * 128;
    size_t tokbase = (size_t)b * Tt;
    int qoff = h * 64, koff = 512 + h * 64, voff = 1024 + h * 64;
    // T**-0.5 * log2(e): softmax computed with exp2, fixed max=0
    const float qscale = 0.022097086912079608f * 1.4426950408889634f;

    // ---- stage Q (pre-scaled) into Qs[q][72], 128 rows
    {
        int q = tid >> 2, dg = (tid & 3) * 16;
        const unsigned short* src = q16 + (tokbase + base + q) * 1536 + qoff + dg;
        uint4 a  = *(const uint4*)src;
        uint4 b4 = *(const uint4*)(src + 8);
        uint4 ra, rb;
        ra.x = scale2(a.x, qscale);  ra.y = scale2(a.y, qscale);
        ra.z = scale2(a.z, qscale);  ra.w = scale2(a.w, qscale);
        rb.x = scale2(b4.x, qscale); rb.y = scale2(b4.y, qscale);
        rb.z = scale2(b4.z, qscale); rb.w = scale2(b4.w, qscale);
        *(uint4*)(Qs + q * 72 + dg)     = ra;
        *(uint4*)(Qs + q * 72 + dg + 8) = rb;
    }
    __syncthreads();
    // ---- extract this wave's Q fragments once (A: m=lane&15=q, k=quad*8+j)
    short8 aq[2];
    aq[0] = *(const short8*)(Qs + (wave * 16 + c) * 72 + g * 8);
    aq[1] = *(const short8*)(Qs + (wave * 16 + c) * 72 + 32 + g * 8);

    short8 ones;
#pragma unroll
    for (int i = 0; i < 8; ++i) ones[i] = (short)0x3F80;   // bf16 1.0

    f32x4 acc[4];
#pragma unroll
    for (int dt = 0; dt < 4; ++dt) acc[dt] = (f32x4){0.f, 0.f, 0.f, 0.f};
    f32x4 accL = (f32x4){0.f, 0.f, 0.f, 0.f};   // row-sums of P
    __hip_bfloat16* Psw = PsS + wave * (16 * 72);
    unsigned short* Psw16 = (unsigned short*)Psw;

    int tmax = 2 * qb + 1;
    for (int tile = 0; tile <= tmax; ++tile) {
        int s0 = tile * 64;
        __syncthreads();                      // prior tile's LDS reads done (also Q frags)
        {   // stage K tile raw: Ks[s][d] (512 threads, 1 uint4 each)
            int s = tid >> 3, dg = (tid & 7) * 8;
            *(uint4*)(KsS + s * 72 + dg) =
                *(const uint4*)(q16 + (tokbase + s0 + s) * 1536 + koff + dg);
        }
        {   // stage V transposed: Vt[d][s], packed u32 (s even/odd pair)
            int sp = (tid & 31) * 2, dg4 = (tid >> 5) * 4;
            const unsigned short* r0p = q16 + (tokbase + s0 + sp) * 1536 + voff + dg4;
            uint2 va = *(const uint2*)r0p;
            uint2 vb = *(const uint2*)(r0p + 1536);
            unsigned a0[2] = {va.x, va.y};
            unsigned b0[2] = {vb.x, vb.y};
#pragma unroll
            for (int i = 0; i < 2; ++i) {
                unsigned p0 = (a0[i] & 0xffffu) | (b0[i] << 16);
                unsigned p1 = (a0[i] >> 16) | (b0[i] & 0xffff0000u);
                *(unsigned*)(VtS + (dg4 + 2 * i) * 72 + sp)     = p0;
                *(unsigned*)(VtS + (dg4 + 2 * i + 1) * 72 + sp) = p1;
            }
        }
        __syncthreads();
        if (tile == tmax && wave < 4) continue;   // fully masked for waves 0-3
        // ---- QK^T: S[16 q][64 s] per wave (base-2 scaled scores)
        f32x4 Sc[4];
#pragma unroll
        for (int st = 0; st < 4; ++st) Sc[st] = (f32x4){0.f, 0.f, 0.f, 0.f};
#pragma unroll
        for (int ks = 0; ks < 2; ++ks)
#pragma unroll
            for (int st = 0; st < 4; ++st) {
                short8 bk = *(const short8*)(KsS + (st * 16 + c) * 72 + ks * 32 + g * 8);
                Sc[st] = __builtin_amdgcn_mfma_f32_16x16x32_bf16(aq[ks], bk, Sc[st], 0, 0, 0);
            }
        if (tile >= 2 * qb) {                 // diagonal-straddling tiles
            int qg = base + wave * 16 + g * 4;
#pragma unroll
            for (int st = 0; st < 4; ++st) {
                int sg = s0 + st * 16 + c;
#pragma unroll
                for (int r = 0; r < 4; ++r)
                    if (sg > qg + r) Sc[st][r] = -1e30f;
            }
        }
        // ---- p = exp2(score); straight to LDS (same-wave region, no barrier)
#pragma unroll
        for (int st = 0; st < 4; ++st)
#pragma unroll
            for (int r = 0; r < 4; ++r)
                Psw16[(g * 4 + r) * 72 + st * 16 + c] =
                    f2bfu(__builtin_amdgcn_exp2f(Sc[st][r]));
        // ---- PV: O[16 q][64 d] accumulate; l via ones-MFMA
#pragma unroll
        for (int ks = 0; ks < 2; ++ks) {
            short8 ap = *(const short8*)(Psw + c * 72 + ks * 32 + g * 8);
            accL = __builtin_amdgcn_mfma_f32_16x16x32_bf16(ap, ones, accL, 0, 0, 0);
#pragma unroll
            for (int dt = 0; dt < 4; ++dt) {
                short8 bv = *(const short8*)(VtS + (dt * 16 + c) * 72 + ks * 32 + g * 8);
                acc[dt] = __builtin_amdgcn_mfma_f32_16x16x32_bf16(ap, bv, acc[dt], 0, 0, 0);
            }
        }
    }
    // ---- epilogue: O[q][d] = acc/l -> o_bf [B*T][512]
    float rl[4];
#pragma unroll
    for (int r = 0; r < 4; ++r) rl[r] = 1.0f / accL[r];
#pragma unroll
    for (int dt = 0; dt < 4; ++dt)
#pragma unroll
        for (int r = 0; r < 4; ++r) {
            int row = base + wave * 16 + g * 4 + r;
            float o = acc[dt][r] * rl[r];
            ob[(tokbase + row) * 512 + h * 64 + dt * 16 + c] = __float2bfloat16(o);
        }
}

// ---------------------------------------------------------------------------
extern "C" void kernel_launch(void* const* d_in, const int* in_sizes, int n_in,
                              void* d_out, int out_size, void* d_ws, size_t ws_size,
                              hipStream_t stream) {
    const float* x   = (const float*)d_in[0];
    const float* Wq  = (const float*)d_in[1];
    const float* Wk  = (const float*)d_in[2];
    const float* Wv  = (const float*)d_in[3];
    const float* Wo  = (const float*)d_in[4];
    const float* bo  = (const float*)d_in[5];
    const float* W1  = (const float*)d_in[6];
    const float* b1  = (const float*)d_in[7];
    const float* W2  = (const float*)d_in[8];
    const float* b2  = (const float*)d_in[9];
    const float* g1  = (const float*)d_in[10];
    const float* be1 = (const float*)d_in[11];
    const float* g2  = (const float*)d_in[12];
    const float* be2 = (const float*)d_in[13];
    float* out = (float*)d_out;

    // Workspace layout (byte offsets, 16B aligned).
    char* ws = (char*)d_ws;
    __hip_bfloat16* bqT    = (__hip_bfloat16*)(ws);                  // [1536][512]
    __hip_bfloat16* woT    = (__hip_bfloat16*)(ws + 1572864);        // [512][512]
    __hip_bfloat16* w1T    = (__hip_bfloat16*)(ws + 2097152);        // [4096][512]
    __hip_bfloat16* w2T    = (__hip_bfloat16*)(ws + 6291456);        // [512][4096]
    float*          xn     = (float*)(ws + 10485760);                // [8192][512] fp32
    __hip_bfloat16* xn_bf  = (__hip_bfloat16*)(ws + 27262976);       // [8192][512] bf16
    __hip_bfloat16* qkv_bf = (__hip_bfloat16*)(ws + 35651584);       // [8192][1536] bf16
    __hip_bfloat16* o_bf   = (__hip_bfloat16*)(ws + 60817408);       // [8192][512] bf16

    // 1. LN1: xn = LN(x)+bo (fp32 residual base), xn_bf = LN(x) (bf16)
    ln_kernel<<<Mrows, 256, 0, stream>>>(x, g1, be1, bo, xn, xn_bf);
    // 2. weight repacks to bf16 [N][K]
    repack_qkv_t<<<192, 256, 0, stream>>>(Wq, Wk, Wv, bqT);
    transpose_bf16<<<dim3(8, 8),  256, 0, stream>>>(Wo, woT, 512, 512);
    transpose_bf16<<<dim3(64, 8), 256, 0, stream>>>(W1, w1T, 512, HIDs);
    transpose_bf16<<<dim3(8, 64), 256, 0, stream>>>(W2, w2T, HIDs, 512);
    // 3. qkv = xn @ Wqkv  -> bf16   (grid 12x64)
    mfma_gemm<<<768, 256, 0, stream>>>(
        xn_bf, 512, bqT, 512, nullptr, qkv_bf, 1536, 512, 0, 12, 64);
    // 4. causal attention (MFMA flash, 128-row Q blocks) -> o_bf
    attn_mfma<<<Bsz * Hh * (Tt / 128), 512, 0, stream>>>(qkv_bf, o_bf);
    // 5. xn(=x2) += o @ Wo   (grid 4x64x2, split-K=2, atomic accumulate)
    mfma_gemm<<<512, 256, 0, stream>>>(
        o_bf, 512, woT, 512, xn, nullptr, 512, 256, 4, 4, 64);
    // 6. LN2: out = LN(x2)+b2 (fp32, final residual base), xn_bf = LN(x2)
    ln_kernel<<<Mrows, 256, 0, stream>>>(xn, g2, be2, b2, out, xn_bf);
    // 7+8. fused FFN: out += relu(xn2@W1+b1)@W2  (256 blocks, 32 rows each)
    ffn_fused<<<256, 256, 0, stream>>>(xn_bf, w1T, w2T, b1, out);
}

// Round 9
// 401.773 us; speedup vs baseline: 1.4972x; 1.4972x over previous
//
#include <hip/hip_runtime.h>
#include <hip/hip_bf16.h>
#include <math.h>

// Problem constants (B,T,E)=(4,2048,512), H=8, D=64, HID=H*E=4096.
#define Bsz 4
#define Tt 2048
#define Ee 512
#define Hh 8
#define Dd 64
#define HIDs 4096
#define Mrows (Bsz * Tt)   // 8192 token rows

typedef __attribute__((ext_vector_type(8))) short short8;   // 8 bf16 (4 VGPRs)
typedef __attribute__((ext_vector_type(4))) float f32x4;    // MFMA accumulator

#define AS1 __attribute__((address_space(1)))
#define AS3 __attribute__((address_space(3)))

__device__ __forceinline__ unsigned short f2bfu(float f) {   // RNE float->bf16 bits
    unsigned u = __float_as_uint(f);
    return (unsigned short)((u + 0x7fffu + ((u >> 16) & 1u)) >> 16);
}
__device__ __forceinline__ unsigned scale2(unsigned w, float s) {  // 2xbf16 *= s
    float lo = __uint_as_float(w << 16) * s;
    float hi = __uint_as_float(w & 0xffff0000u) * s;
    return (unsigned)f2bfu(lo) | ((unsigned)f2bfu(hi) << 16);
}

// ---------------------------------------------------------------------------
// LayerNorm: one 256-thread block per row of 512. Input = x (+ optional
// partial P, folding the Wo split-K partial into LN2's input read).
// out_f = LN(v)*g+b + addb[col]  (fp32; addb folds the NEXT stage's bias)
// out_bf = LN(v)*g+b             (bf16 GEMM operand, no addb)
__global__ __launch_bounds__(256) void ln_kernel(const float* __restrict__ x,
        const float* __restrict__ g, const float* __restrict__ b,
        const float* __restrict__ addb, const float* __restrict__ part,
        float* __restrict__ out_f, __hip_bfloat16* __restrict__ out_bf) {
    int row = blockIdx.x;
    int tid = threadIdx.x;
    const float* xr = x + (size_t)row * Ee;
    float v0 = xr[tid];
    float v1 = xr[tid + 256];
    if (part) {
        const float* pr = part + (size_t)row * Ee;
        v0 += pr[tid];
        v1 += pr[tid + 256];
    }
    float s = v0 + v1;
    float sq = v0 * v0 + v1 * v1;
#pragma unroll
    for (int off = 32; off > 0; off >>= 1) {
        s  += __shfl_xor(s, off, 64);
        sq += __shfl_xor(sq, off, 64);
    }
    __shared__ float ls[4], lq[4];
    int wid = tid >> 6, lane = tid & 63;
    if (lane == 0) { ls[wid] = s; lq[wid] = sq; }
    __syncthreads();
    s  = ls[0] + ls[1] + ls[2] + ls[3];
    sq = lq[0] + lq[1] + lq[2] + lq[3];
    float mean = s * (1.0f / Ee);
    float var  = sq * (1.0f / Ee) - mean * mean;   // biased var, like jnp.var
    float rstd = rsqrtf(var + 1e-5f);
    float o0 = (v0 - mean) * rstd * g[tid]       + b[tid];
    float o1 = (v1 - mean) * rstd * g[tid + 256] + b[tid + 256];
    float* orow = out_f + (size_t)row * Ee;
    orow[tid]       = o0 + addb[tid];
    orow[tid + 256] = o1 + addb[tid + 256];
    __hip_bfloat16* brow = out_bf + (size_t)row * Ee;
    brow[tid]       = __float2bfloat16(o0);
    brow[tid + 256] = __float2bfloat16(o1);
}

// ---------------------------------------------------------------------------
// out4 += P4  (final FFN2 partial merge), float4-vectorized.
__global__ __launch_bounds__(256) void add_kernel(const float4* __restrict__ P,
        float4* __restrict__ out) {
    int i = blockIdx.x * 256 + threadIdx.x;
    float4 o = out[i], p = P[i];
    o.x += p.x; o.y += p.y; o.z += p.z; o.w += p.w;
    out[i] = o;
}

// ---------------------------------------------------------------------------
// Generic fp32 [R][C] -> bf16 [C][R] transpose, 64x64 LDS tiles.
__global__ __launch_bounds__(256) void transpose_bf16(const float* __restrict__ in,
        __hip_bfloat16* __restrict__ outp, int R, int C) {
    __shared__ float tile[64][65];
    int c0 = blockIdx.x * 64, r0 = blockIdx.y * 64;
    int tc = threadIdx.x & 63, tg = threadIdx.x >> 6;
#pragma unroll
    for (int i = 0; i < 16; ++i) {
        int r = tg * 16 + i;
        tile[r][tc] = in[(size_t)(r0 + r) * C + c0 + tc];
    }
    __syncthreads();
#pragma unroll
    for (int i = 0; i < 16; ++i) {
        int cc = tg * 16 + i;
        outp[(size_t)(c0 + cc) * R + r0 + tc] = __float2bfloat16(tile[tc][cc]);
    }
}

// ---------------------------------------------------------------------------
// Repack Wq/Wk/Wv [H,E,D] fp32 -> bqT [3*H*D][E] bf16 (row c=p*512+h*64+d).
__global__ __launch_bounds__(256) void repack_qkv_t(const float* __restrict__ Wq,
        const float* __restrict__ Wk, const float* __restrict__ Wv,
        __hip_bfloat16* __restrict__ bqT) {
    int blk = blockIdx.x;            // p*64 + h*8 + et
    int p = blk >> 6, h = (blk >> 3) & 7, et = blk & 7;
    const float* W = (p == 0) ? Wq : ((p == 1) ? Wk : Wv);
    __shared__ float tile[64][65];
    int td = threadIdx.x & 63, tg = threadIdx.x >> 6;
#pragma unroll
    for (int i = 0; i < 16; ++i) {
        int e = tg * 16 + i;
        tile[e][td] = W[((size_t)h * Ee + et * 64 + e) * Dd + td];
    }
    __syncthreads();
#pragma unroll
    for (int i = 0; i < 16; ++i) {
        int d = tg * 16 + i;
        bqT[((size_t)(p * 512 + h * 64 + d)) * Ee + et * 64 + td] = __float2bfloat16(tile[td][d]);
    }
}

// ---------------------------------------------------------------------------
// bf16 MFMA GEMM: 128x128 tile, BK=64 as two 32-wide k-panels,
// global_load_lds width 16. 1D grid with XCD-aware swizzle. Split-K (2) via
// virtual z, NO atomics:
//   mode 0: Cb[ci] = bf16(acc)                      (qkv projection)
//   mode 1: bz==0 -> Cf[ci] += acc (plain RMW);     (split-2 accumulate)
//           bz==1 -> Pf[ci]  = acc (plain store)
__global__ __launch_bounds__(256) void mfma_gemm(
        const __hip_bfloat16* __restrict__ A, int lda,
        const __hip_bfloat16* __restrict__ B, int ldb,
        float* __restrict__ Cf, float* __restrict__ Pf,
        __hip_bfloat16* __restrict__ Cb, int ldc, int Kc,
        int mode, int nx, int ny) {
    __shared__ __hip_bfloat16 As[2 * 128 * 32];   // [panel][m][k32]
    __shared__ __hip_bfloat16 Bs[2 * 128 * 32];   // [panel][n][k32]
    int tid = threadIdx.x;
    int lane = tid & 63, wave = tid >> 6;
    int wm = wave >> 1, wn = wave & 1;
    int L = blockIdx.x;
    int slots = (int)gridDim.x >> 3;
    int v = (L & 7) * slots + (L >> 3);
    int bx = v % nx;
    int rem = v / nx;
    int by = rem % ny;
    int bz = rem / ny;
    int row0 = by * 128, col0 = bx * 128;
    int kbase = bz * Kc;
    f32x4 acc[4][4];
#pragma unroll
    for (int i = 0; i < 4; ++i)
#pragma unroll
        for (int j = 0; j < 4; ++j) acc[i][j] = (f32x4){0.f, 0.f, 0.f, 0.f};

    int fr = lane & 15;
    int kq = (lane >> 4) << 3;            // fragment k-offset: 0/8/16/24

    for (int k0 = kbase; k0 < kbase + Kc; k0 += 64) {
        __syncthreads();
#pragma unroll
        for (int j = 0; j < 4; ++j) {
            int c  = j * 256 + tid;
            int cb = j * 256 + wave * 64;         // wave-uniform base chunk
            int p  = c >> 9, cp = c & 511;
            int r  = cp >> 2, kg = (cp & 3) << 3;
            int ko = k0 + p * 32 + kg;
            __builtin_amdgcn_global_load_lds(
                (const AS1 void*)(A + (size_t)(row0 + r) * lda + ko),
                (AS3 void*)(As + cb * 8), 16, 0, 0);
            __builtin_amdgcn_global_load_lds(
                (const AS1 void*)(B + (size_t)(col0 + r) * ldb + ko),
                (AS3 void*)(Bs + cb * 8), 16, 0, 0);
        }
        __syncthreads();
#pragma unroll
        for (int ks = 0; ks < 2; ++ks) {
            short8 afr[4], bfr[4];
#pragma unroll
            for (int i = 0; i < 4; ++i) {
                afr[i] = *(const short8*)(As + ks * 4096 + (wm * 64 + i * 16 + fr) * 32 + kq);
                bfr[i] = *(const short8*)(Bs + ks * 4096 + (wn * 64 + i * 16 + fr) * 32 + kq);
            }
#pragma unroll
            for (int i = 0; i < 4; ++i)
#pragma unroll
                for (int j = 0; j < 4; ++j)
                    acc[i][j] = __builtin_amdgcn_mfma_f32_16x16x32_bf16(afr[i], bfr[j], acc[i][j], 0, 0, 0);
        }
    }
    int rq = (lane >> 4) << 2;
#pragma unroll
    for (int i = 0; i < 4; ++i) {
#pragma unroll
        for (int j = 0; j < 4; ++j) {
#pragma unroll
            for (int gidx = 0; gidx < 4; ++gidx) {
                int r = row0 + wm * 64 + i * 16 + rq + gidx;
                int c = col0 + wn * 64 + j * 16 + fr;
                size_t ci = (size_t)r * ldc + c;
                float val = acc[i][j][gidx];
                if (mode == 0) {
                    Cb[ci] = __float2bfloat16(val);
                } else if (bz == 0) {
                    Cf[ci] += val;          // plain RMW (exclusive tile)
                } else {
                    Pf[ci] = val;           // partial store, merged downstream
                }
            }
        }
    }
}

// ---------------------------------------------------------------------------
// bf16 MFMA GEMM, 256x128 tile (FFN1): BK=64 two-panel LDS, 4 waves x 64
// rows x 128 cols each. Epilogue: Cb = bf16(relu(acc + bias[c])).
__global__ __launch_bounds__(256) void mfma_gemm256(
        const __hip_bfloat16* __restrict__ A, int lda,
        const __hip_bfloat16* __restrict__ B, int ldb,
        __hip_bfloat16* __restrict__ Cb, int ldc, int K,
        const float* __restrict__ bias, int nx) {
    __shared__ __hip_bfloat16 As[2 * 256 * 32];   // 32 KB [panel][m][k32]
    __shared__ __hip_bfloat16 Bs[2 * 128 * 32];   // 16 KB [panel][n][k32]
    int tid = threadIdx.x;
    int lane = tid & 63, wave = tid >> 6;
    int L = blockIdx.x;
    int slots = (int)gridDim.x >> 3;
    int v = (L & 7) * slots + (L >> 3);
    int bx = v % nx, by = v / nx;
    int row0 = by * 256, col0 = bx * 128;
    f32x4 acc[4][8];
#pragma unroll
    for (int i = 0; i < 4; ++i)
#pragma unroll
        for (int j = 0; j < 8; ++j) acc[i][j] = (f32x4){0.f, 0.f, 0.f, 0.f};

    int fr = lane & 15;
    int kq = (lane >> 4) << 3;

    for (int k0 = 0; k0 < K; k0 += 64) {
        __syncthreads();
        // A: 2048 chunks (2 panels x 256 r x 4 kg)
#pragma unroll
        for (int j = 0; j < 8; ++j) {
            int c  = j * 256 + tid;
            int cb = j * 256 + wave * 64;
            int p  = c >> 10, cp = c & 1023;
            int r  = cp >> 2, kg = (cp & 3) << 3;
            int ko = k0 + p * 32 + kg;
            __builtin_amdgcn_global_load_lds(
                (const AS1 void*)(A + (size_t)(row0 + r) * lda + ko),
                (AS3 void*)(As + cb * 8), 16, 0, 0);
        }
        // B: 1024 chunks
#pragma unroll
        for (int j = 0; j < 4; ++j) {
            int c  = j * 256 + tid;
            int cb = j * 256 + wave * 64;
            int p  = c >> 9, cp = c & 511;
            int r  = cp >> 2, kg = (cp & 3) << 3;
            int ko = k0 + p * 32 + kg;
            __builtin_amdgcn_global_load_lds(
                (const AS1 void*)(B + (size_t)(col0 + r) * ldb + ko),
                (AS3 void*)(Bs + cb * 8), 16, 0, 0);
        }
        __syncthreads();
#pragma unroll
        for (int ks = 0; ks < 2; ++ks) {
            short8 afr[4], bfr[8];
#pragma unroll
            for (int i = 0; i < 4; ++i)
                afr[i] = *(const short8*)(As + ks * 8192 + (wave * 64 + i * 16 + fr) * 32 + kq);
#pragma unroll
            for (int j = 0; j < 8; ++j)
                bfr[j] = *(const short8*)(Bs + ks * 4096 + (j * 16 + fr) * 32 + kq);
#pragma unroll
            for (int i = 0; i < 4; ++i)
#pragma unroll
                for (int j = 0; j < 8; ++j)
                    acc[i][j] = __builtin_amdgcn_mfma_f32_16x16x32_bf16(afr[i], bfr[j], acc[i][j], 0, 0, 0);
        }
    }
    int rq = (lane >> 4) << 2;
    float bv[8];
#pragma unroll
    for (int j = 0; j < 8; ++j) bv[j] = bias[col0 + j * 16 + fr];
#pragma unroll
    for (int i = 0; i < 4; ++i) {
#pragma unroll
        for (int j = 0; j < 8; ++j) {
#pragma unroll
            for (int gidx = 0; gidx < 4; ++gidx) {
                int r = row0 + wave * 64 + i * 16 + rq + gidx;
                int c = col0 + j * 16 + fr;
                float t = acc[i][j][gidx] + bv[j];
                Cb[(size_t)r * ldc + c] = __float2bfloat16(t > 0.f ? t : 0.f);
            }
        }
    }
}

// ---------------------------------------------------------------------------
// MFMA flash attention, no-max softmax. One block = 128 Q rows of one (b,h);
// 8 waves x 16 rows. Scores are bounded (LN-scale inputs, T^-0.5 scale), so
// exp2 without max subtraction is safe -> no cross-lane reductions at all.
// Row-sum l accumulated on the matrix pipe via a B=ones MFMA.
__global__ __launch_bounds__(512) void attn_mfma(const __hip_bfloat16* __restrict__ qkvb,
        __hip_bfloat16* __restrict__ ob) {
    __shared__ __hip_bfloat16 KsS[64 * 72];     // K tile [s][d], pad 72
    __shared__ __hip_bfloat16 VtS[64 * 72];     // V^T tile [d][s], pad 72
    __shared__ __hip_bfloat16 PsS[8 * 16 * 72]; // P [wave][q][s] bf16; Q overlays
    __hip_bfloat16* Qs = PsS;                   // Q staging [128 q][72]

    const unsigned short* q16 = (const unsigned short*)qkvb;
    int tid  = threadIdx.x;
    int lane = tid & 63, wave = tid >> 6;
    int g = lane >> 4, c = lane & 15;
    int blk = blockIdx.x;
    int qb  = 15 - (blk >> 5);                // global heavy-first
    int bh  = blk & 31;
    int b = bh >> 3, h = bh & 7;
    int base = qb * 128;
    size_t tokbase = (size_t)b * Tt;
    int qoff = h * 64, koff = 512 + h * 64, voff = 1024 + h * 64;
    // T**-0.5 * log2(e): softmax computed with exp2, fixed max=0
    const float qscale = 0.022097086912079608f * 1.4426950408889634f;

    // ---- stage Q (pre-scaled) into Qs[q][72], 128 rows
    {
        int q = tid >> 2, dg = (tid & 3) * 16;
        const unsigned short* src = q16 + (tokbase + base + q) * 1536 + qoff + dg;
        uint4 a  = *(const uint4*)src;
        uint4 b4 = *(const uint4*)(src + 8);
        uint4 ra, rb;
        ra.x = scale2(a.x, qscale);  ra.y = scale2(a.y, qscale);
        ra.z = scale2(a.z, qscale);  ra.w = scale2(a.w, qscale);
        rb.x = scale2(b4.x, qscale); rb.y = scale2(b4.y, qscale);
        rb.z = scale2(b4.z, qscale); rb.w = scale2(b4.w, qscale);
        *(uint4*)(Qs + q * 72 + dg)     = ra;
        *(uint4*)(Qs + q * 72 + dg + 8) = rb;
    }
    __syncthreads();
    // ---- extract this wave's Q fragments once (A: m=lane&15=q, k=quad*8+j)
    short8 aq[2];
    aq[0] = *(const short8*)(Qs + (wave * 16 + c) * 72 + g * 8);
    aq[1] = *(const short8*)(Qs + (wave * 16 + c) * 72 + 32 + g * 8);

    short8 ones;
#pragma unroll
    for (int i = 0; i < 8; ++i) ones[i] = (short)0x3F80;   // bf16 1.0

    f32x4 acc[4];
#pragma unroll
    for (int dt = 0; dt < 4; ++dt) acc[dt] = (f32x4){0.f, 0.f, 0.f, 0.f};
    f32x4 accL = (f32x4){0.f, 0.f, 0.f, 0.f};   // row-sums of P
    __hip_bfloat16* Psw = PsS + wave * (16 * 72);
    unsigned short* Psw16 = (unsigned short*)Psw;

    int tmax = 2 * qb + 1;
    for (int tile = 0; tile <= tmax; ++tile) {
        int s0 = tile * 64;
        __syncthreads();                      // prior tile's LDS reads done (also Q frags)
        {   // stage K tile raw: Ks[s][d] (512 threads, 1 uint4 each)
            int s = tid >> 3, dg = (tid & 7) * 8;
            *(uint4*)(KsS + s * 72 + dg) =
                *(const uint4*)(q16 + (tokbase + s0 + s) * 1536 + koff + dg);
        }
        {   // stage V transposed: Vt[d][s], packed u32 (s even/odd pair)
            int sp = (tid & 31) * 2, dg4 = (tid >> 5) * 4;
            const unsigned short* r0p = q16 + (tokbase + s0 + sp) * 1536 + voff + dg4;
            uint2 va = *(const uint2*)r0p;
            uint2 vb = *(const uint2*)(r0p + 1536);
            unsigned a0[2] = {va.x, va.y};
            unsigned b0[2] = {vb.x, vb.y};
#pragma unroll
            for (int i = 0; i < 2; ++i) {
                unsigned p0 = (a0[i] & 0xffffu) | (b0[i] << 16);
                unsigned p1 = (a0[i] >> 16) | (b0[i] & 0xffff0000u);
                *(unsigned*)(VtS + (dg4 + 2 * i) * 72 + sp)     = p0;
                *(unsigned*)(VtS + (dg4 + 2 * i + 1) * 72 + sp) = p1;
            }
        }
        __syncthreads();
        if (tile == tmax && wave < 4) continue;   // fully masked for waves 0-3
        // ---- QK^T: S[16 q][64 s] per wave (base-2 scaled scores)
        f32x4 Sc[4];
#pragma unroll
        for (int st = 0; st < 4; ++st) Sc[st] = (f32x4){0.f, 0.f, 0.f, 0.f};
#pragma unroll
        for (int ks = 0; ks < 2; ++ks)
#pragma unroll
            for (int st = 0; st < 4; ++st) {
                short8 bk = *(const short8*)(KsS + (st * 16 + c) * 72 + ks * 32 + g * 8);
                Sc[st] = __builtin_amdgcn_mfma_f32_16x16x32_bf16(aq[ks], bk, Sc[st], 0, 0, 0);
            }
        if (tile >= 2 * qb) {                 // diagonal-straddling tiles
            int qg = base + wave * 16 + g * 4;
#pragma unroll
            for (int st = 0; st < 4; ++st) {
                int sg = s0 + st * 16 + c;
#pragma unroll
                for (int r = 0; r < 4; ++r)
                    if (sg > qg + r) Sc[st][r] = -1e30f;
            }
        }
        // ---- p = exp2(score); straight to LDS (same-wave region, no barrier)
#pragma unroll
        for (int st = 0; st < 4; ++st)
#pragma unroll
            for (int r = 0; r < 4; ++r)
                Psw16[(g * 4 + r) * 72 + st * 16 + c] =
                    f2bfu(__builtin_amdgcn_exp2f(Sc[st][r]));
        // ---- PV: O[16 q][64 d] accumulate; l via ones-MFMA
#pragma unroll
        for (int ks = 0; ks < 2; ++ks) {
            short8 ap = *(const short8*)(Psw + c * 72 + ks * 32 + g * 8);
            accL = __builtin_amdgcn_mfma_f32_16x16x32_bf16(ap, ones, accL, 0, 0, 0);
#pragma unroll
            for (int dt = 0; dt < 4; ++dt) {
                short8 bv = *(const short8*)(VtS + (dt * 16 + c) * 72 + ks * 32 + g * 8);
                acc[dt] = __builtin_amdgcn_mfma_f32_16x16x32_bf16(ap, bv, acc[dt], 0, 0, 0);
            }
        }
    }
    // ---- epilogue: O[q][d] = acc/l -> o_bf [B*T][512]
    float rl[4];
#pragma unroll
    for (int r = 0; r < 4; ++r) rl[r] = 1.0f / accL[r];
#pragma unroll
    for (int dt = 0; dt < 4; ++dt)
#pragma unroll
        for (int r = 0; r < 4; ++r) {
            int row = base + wave * 16 + g * 4 + r;
            float o = acc[dt][r] * rl[r];
            ob[(tokbase + row) * 512 + h * 64 + dt * 16 + c] = __float2bfloat16(o);
        }
}

// ---------------------------------------------------------------------------
extern "C" void kernel_launch(void* const* d_in, const int* in_sizes, int n_in,
                              void* d_out, int out_size, void* d_ws, size_t ws_size,
                              hipStream_t stream) {
    const float* x   = (const float*)d_in[0];
    const float* Wq  = (const float*)d_in[1];
    const float* Wk  = (const float*)d_in[2];
    const float* Wv  = (const float*)d_in[3];
    const float* Wo  = (const float*)d_in[4];
    const float* bo  = (const float*)d_in[5];
    const float* W1  = (const float*)d_in[6];
    const float* b1  = (const float*)d_in[7];
    const float* W2  = (const float*)d_in[8];
    const float* b2  = (const float*)d_in[9];
    const float* g1  = (const float*)d_in[10];
    const float* be1 = (const float*)d_in[11];
    const float* g2  = (const float*)d_in[12];
    const float* be2 = (const float*)d_in[13];
    float* out = (float*)d_out;

    // Workspace layout (byte offsets, 16B aligned). Peak ~103 MB.
    char* ws = (char*)d_ws;
    __hip_bfloat16* bqT    = (__hip_bfloat16*)(ws);                  // [1536][512]
    __hip_bfloat16* woT    = (__hip_bfloat16*)(ws + 1572864);        // [512][512]
    __hip_bfloat16* w1T    = (__hip_bfloat16*)(ws + 2097152);        // [4096][512]
    __hip_bfloat16* w2T    = (__hip_bfloat16*)(ws + 6291456);        // [512][4096]
    float*          xn     = (float*)(ws + 10485760);                // [8192][512] fp32 (LN1+bo, Wo z0 RMW)
    __hip_bfloat16* xn_bf  = (__hip_bfloat16*)(ws + 27262976);       // [8192][512] bf16
    __hip_bfloat16* qkv_bf = (__hip_bfloat16*)(ws + 35651584);       // [8192][1536] bf16
    __hip_bfloat16* o_bf   = (__hip_bfloat16*)(ws + 60817408);       // [8192][512] bf16
    float*          P0     = (float*)(ws + 69206016);                // [8192][512] fp32 Wo z1 partial
    __hip_bfloat16* h_bf   = (__hip_bfloat16*)(ws + 35651584);       // [8192][4096] overlay (qkv/o/P0 dead)
    float*          P2     = (float*)(ws + 10485760);                // FFN2 z1 partial (overlays dead xn)

    // 1. LN1: xn = LN(x)+bo (fp32 residual base), xn_bf = LN(x) (bf16)
    ln_kernel<<<Mrows, 256, 0, stream>>>(x, g1, be1, bo, nullptr, xn, xn_bf);
    // 2. weight repacks to bf16 [N][K]
    repack_qkv_t<<<192, 256, 0, stream>>>(Wq, Wk, Wv, bqT);
    transpose_bf16<<<dim3(8, 8),  256, 0, stream>>>(Wo, woT, 512, 512);
    transpose_bf16<<<dim3(64, 8), 256, 0, stream>>>(W1, w1T, 512, HIDs);
    transpose_bf16<<<dim3(8, 64), 256, 0, stream>>>(W2, w2T, HIDs, 512);
    // 3. qkv = xn @ Wqkv  -> bf16   (grid 12x64)
    mfma_gemm<<<768, 256, 0, stream>>>(
        xn_bf, 512, bqT, 512, nullptr, nullptr, qkv_bf, 1536, 512, 0, 12, 64);
    // 4. causal attention (MFMA flash, 128-row Q blocks) -> o_bf
    attn_mfma<<<Bsz * Hh * (Tt / 128), 512, 0, stream>>>(qkv_bf, o_bf);
    // 5. o @ Wo: split-2, z0 -> xn += acc (plain RMW), z1 -> P0 = acc
    mfma_gemm<<<512, 256, 0, stream>>>(
        o_bf, 512, woT, 512, xn, P0, nullptr, 512, 256, 1, 4, 64);
    // 6. LN2 on x2 = xn + P0: out = LN(x2)+b2, xn_bf = LN(x2)
    ln_kernel<<<Mrows, 256, 0, stream>>>(xn, g2, be2, b2, P0, out, xn_bf);
    // 7. h = relu(xn2 @ W1 + b1)  (256x128 tiles, grid 32x32)
    mfma_gemm256<<<1024, 256, 0, stream>>>(
        xn_bf, 512, w1T, 512, h_bf, HIDs, 512, b1, 32);
    // 8. h @ W2: split-2, z0 -> out += acc (plain RMW), z1 -> P2 = acc
    mfma_gemm<<<512, 256, 0, stream>>>(
        h_bf, HIDs, w2T, HIDs, out, P2, nullptr, 512, 2048, 1, 4, 64);
    // 9. out += P2
    add_kernel<<<4096, 256, 0, stream>>>((const float4*)P2, (float4*)out);
}

// Round 10
// 355.247 us; speedup vs baseline: 1.6933x; 1.1310x over previous
//
#include <hip/hip_runtime.h>
#include <hip/hip_bf16.h>
#include <math.h>

// Problem constants (B,T,E)=(4,2048,512), H=8, D=64, HID=H*E=4096.
#define Bsz 4
#define Tt 2048
#define Ee 512
#define Hh 8
#define Dd 64
#define HIDs 4096
#define Mrows (Bsz * Tt)   // 8192 token rows

typedef __attribute__((ext_vector_type(8))) short short8;   // 8 bf16 (4 VGPRs)
typedef __attribute__((ext_vector_type(4))) float f32x4;    // MFMA accumulator

#define AS1 __attribute__((address_space(1)))
#define AS3 __attribute__((address_space(3)))

__device__ __forceinline__ unsigned short f2bfu(float f) {   // RNE float->bf16 bits
    unsigned u = __float_as_uint(f);
    return (unsigned short)((u + 0x7fffu + ((u >> 16) & 1u)) >> 16);
}
__device__ __forceinline__ unsigned short truncbf(float f) { // truncating (P only)
    return (unsigned short)(__float_as_uint(f) >> 16);
}
__device__ __forceinline__ unsigned scale2(unsigned w, float s) {  // 2xbf16 *= s
    float lo = __uint_as_float(w << 16) * s;
    float hi = __uint_as_float(w & 0xffff0000u) * s;
    return (unsigned)f2bfu(lo) | ((unsigned)f2bfu(hi) << 16);
}

// ---------------------------------------------------------------------------
// LayerNorm: one 256-thread block per row of 512.
// out_f = LN(x)*g+b + addb[col]  (fp32; addb folds the NEXT stage's bias)
// out_bf = LN(x)*g+b             (bf16 GEMM operand, no addb)
__global__ __launch_bounds__(256) void ln_kernel(const float* __restrict__ x,
        const float* __restrict__ g, const float* __restrict__ b,
        const float* __restrict__ addb,
        float* __restrict__ out_f, __hip_bfloat16* __restrict__ out_bf) {
    int row = blockIdx.x;
    int tid = threadIdx.x;
    const float* xr = x + (size_t)row * Ee;
    float v0 = xr[tid];
    float v1 = xr[tid + 256];
    float s = v0 + v1;
    float sq = v0 * v0 + v1 * v1;
#pragma unroll
    for (int off = 32; off > 0; off >>= 1) {
        s  += __shfl_xor(s, off, 64);
        sq += __shfl_xor(sq, off, 64);
    }
    __shared__ float ls[4], lq[4];
    int wid = tid >> 6, lane = tid & 63;
    if (lane == 0) { ls[wid] = s; lq[wid] = sq; }
    __syncthreads();
    s  = ls[0] + ls[1] + ls[2] + ls[3];
    sq = lq[0] + lq[1] + lq[2] + lq[3];
    float mean = s * (1.0f / Ee);
    float var  = sq * (1.0f / Ee) - mean * mean;   // biased var, like jnp.var
    float rstd = rsqrtf(var + 1e-5f);
    float o0 = (v0 - mean) * rstd * g[tid]       + b[tid];
    float o1 = (v1 - mean) * rstd * g[tid + 256] + b[tid + 256];
    float* orow = out_f + (size_t)row * Ee;
    orow[tid]       = o0 + addb[tid];
    orow[tid + 256] = o1 + addb[tid + 256];
    __hip_bfloat16* brow = out_bf + (size_t)row * Ee;
    brow[tid]       = __float2bfloat16(o0);
    brow[tid + 256] = __float2bfloat16(o1);
}

// ---------------------------------------------------------------------------
// All weight repacks in ONE dispatch (block-id ranges):
//   [0,192)     Wq/Wk/Wv [H,E,D] -> bqT [1536][512]
//   [192,256)   Wo  [512][512]   -> woT [512][512]
//   [256,768)   W1  [512][4096]  -> w1T [4096][512]
//   [768,1280)  W2  [4096][512]  -> w2T [512][4096]
__device__ __forceinline__ void tr_tile(const float* __restrict__ in,
        __hip_bfloat16* __restrict__ outp, int R, int C, int c0, int r0) {
    __shared__ float tile[64][65];
    int tc = threadIdx.x & 63, tg = threadIdx.x >> 6;
#pragma unroll
    for (int i = 0; i < 16; ++i) {
        int r = tg * 16 + i;
        tile[r][tc] = in[(size_t)(r0 + r) * C + c0 + tc];
    }
    __syncthreads();
#pragma unroll
    for (int i = 0; i < 16; ++i) {
        int cc = tg * 16 + i;
        outp[(size_t)(c0 + cc) * R + r0 + tc] = __float2bfloat16(tile[tc][cc]);
    }
}
__global__ __launch_bounds__(256) void repack_all(const float* __restrict__ Wq,
        const float* __restrict__ Wk, const float* __restrict__ Wv,
        const float* __restrict__ Wo, const float* __restrict__ W1,
        const float* __restrict__ W2, __hip_bfloat16* __restrict__ bqT,
        __hip_bfloat16* __restrict__ woT, __hip_bfloat16* __restrict__ w1T,
        __hip_bfloat16* __restrict__ w2T) {
    int blk = blockIdx.x;
    if (blk < 192) {                 // qkv: p*64 + h*8 + et
        int p = blk >> 6, h = (blk >> 3) & 7, et = blk & 7;
        const float* W = (p == 0) ? Wq : ((p == 1) ? Wk : Wv);
        __shared__ float tile[64][65];
        int td = threadIdx.x & 63, tg = threadIdx.x >> 6;
#pragma unroll
        for (int i = 0; i < 16; ++i) {
            int e = tg * 16 + i;
            tile[e][td] = W[((size_t)h * Ee + et * 64 + e) * Dd + td];
        }
        __syncthreads();
#pragma unroll
        for (int i = 0; i < 16; ++i) {
            int d = tg * 16 + i;
            bqT[((size_t)(p * 512 + h * 64 + d)) * Ee + et * 64 + td] =
                __float2bfloat16(tile[td][d]);
        }
    } else if (blk < 256) {
        int t = blk - 192;           // 8x8
        tr_tile(Wo, woT, 512, 512, (t & 7) * 64, (t >> 3) * 64);
    } else if (blk < 768) {
        int t = blk - 256;           // 64x8
        tr_tile(W1, w1T, 512, HIDs, (t & 63) * 64, (t >> 6) * 64);
    } else {
        int t = blk - 768;           // 8x64
        tr_tile(W2, w2T, HIDs, 512, (t & 7) * 64, (t >> 3) * 64);
    }
}

// ---------------------------------------------------------------------------
// bf16 MFMA GEMM: 128x128 tile, BK=64 two-panel LDS, global_load_lds w=16.
// XCD swizzle (contiguous v per XCD). Epilogue: Cb = bf16(acc). (QKV only.)
__global__ __launch_bounds__(256) void mfma_gemm(
        const __hip_bfloat16* __restrict__ A, int lda,
        const __hip_bfloat16* __restrict__ B, int ldb,
        __hip_bfloat16* __restrict__ Cb, int ldc, int K, int nx) {
    __shared__ __hip_bfloat16 As[2 * 128 * 32];
    __shared__ __hip_bfloat16 Bs[2 * 128 * 32];
    int tid = threadIdx.x;
    int lane = tid & 63, wave = tid >> 6;
    int wm = wave >> 1, wn = wave & 1;
    int L = blockIdx.x;
    int slots = (int)gridDim.x >> 3;
    int v = (L & 7) * slots + (L >> 3);
    int bx = v % nx, by = v / nx;
    int row0 = by * 128, col0 = bx * 128;
    f32x4 acc[4][4];
#pragma unroll
    for (int i = 0; i < 4; ++i)
#pragma unroll
        for (int j = 0; j < 4; ++j) acc[i][j] = (f32x4){0.f, 0.f, 0.f, 0.f};

    int fr = lane & 15;
    int kq = (lane >> 4) << 3;

    for (int k0 = 0; k0 < K; k0 += 64) {
        __syncthreads();
#pragma unroll
        for (int j = 0; j < 4; ++j) {
            int c  = j * 256 + tid;
            int cb = j * 256 + wave * 64;
            int p  = c >> 9, cp = c & 511;
            int r  = cp >> 2, kg = (cp & 3) << 3;
            int ko = k0 + p * 32 + kg;
            __builtin_amdgcn_global_load_lds(
                (const AS1 void*)(A + (size_t)(row0 + r) * lda + ko),
                (AS3 void*)(As + cb * 8), 16, 0, 0);
            __builtin_amdgcn_global_load_lds(
                (const AS1 void*)(B + (size_t)(col0 + r) * ldb + ko),
                (AS3 void*)(Bs + cb * 8), 16, 0, 0);
        }
        __syncthreads();
#pragma unroll
        for (int ks = 0; ks < 2; ++ks) {
            short8 afr[4], bfr[4];
#pragma unroll
            for (int i = 0; i < 4; ++i) {
                afr[i] = *(const short8*)(As + ks * 4096 + (wm * 64 + i * 16 + fr) * 32 + kq);
                bfr[i] = *(const short8*)(Bs + ks * 4096 + (wn * 64 + i * 16 + fr) * 32 + kq);
            }
#pragma unroll
            for (int i = 0; i < 4; ++i)
#pragma unroll
                for (int j = 0; j < 4; ++j)
                    acc[i][j] = __builtin_amdgcn_mfma_f32_16x16x32_bf16(afr[i], bfr[j], acc[i][j], 0, 0, 0);
        }
    }
    int rq = (lane >> 4) << 2;
#pragma unroll
    for (int i = 0; i < 4; ++i)
#pragma unroll
        for (int j = 0; j < 4; ++j)
#pragma unroll
            for (int gidx = 0; gidx < 4; ++gidx) {
                int r = row0 + wm * 64 + i * 16 + rq + gidx;
                int c = col0 + wn * 64 + j * 16 + fr;
                Cb[(size_t)r * ldc + c] = __float2bfloat16(acc[i][j][gidx]);
            }
}

// ---------------------------------------------------------------------------
// bf16 MFMA GEMM, 128x64 tile, full K (no split, no atomics). 4 waves x
// (32m x 64n). Epilogue: Cf[ci] += acc (plain RMW, exclusive tile).
// Used for Wo (K=512) and FFN2 (K=4096 -- 64-iteration K loop).
__global__ __launch_bounds__(256) void mfma_gemm_n64(
        const __hip_bfloat16* __restrict__ A, int lda,
        const __hip_bfloat16* __restrict__ B, int ldb,
        float* __restrict__ Cf, int ldc, int K, int nx) {
    __shared__ __hip_bfloat16 As[2 * 128 * 32];   // 16 KB
    __shared__ __hip_bfloat16 Bs[2 * 64 * 32];    //  8 KB
    int tid = threadIdx.x;
    int lane = tid & 63, wave = tid >> 6;
    int L = blockIdx.x;
    int slots = (int)gridDim.x >> 3;
    int v = (L & 7) * slots + (L >> 3);
    int bx = v % nx, by = v / nx;
    int row0 = by * 128, col0 = bx * 64;
    f32x4 acc[2][4];
#pragma unroll
    for (int i = 0; i < 2; ++i)
#pragma unroll
        for (int j = 0; j < 4; ++j) acc[i][j] = (f32x4){0.f, 0.f, 0.f, 0.f};

    int fr = lane & 15;
    int kq = (lane >> 4) << 3;

    for (int k0 = 0; k0 < K; k0 += 64) {
        __syncthreads();
        // A: 1024 chunks (2 panels x 128 r x 4 kg) -> 4 per thread
#pragma unroll
        for (int j = 0; j < 4; ++j) {
            int c  = j * 256 + tid;
            int cb = j * 256 + wave * 64;
            int p  = c >> 9, cp = c & 511;
            int r  = cp >> 2, kg = (cp & 3) << 3;
            __builtin_amdgcn_global_load_lds(
                (const AS1 void*)(A + (size_t)(row0 + r) * lda + k0 + p * 32 + kg),
                (AS3 void*)(As + cb * 8), 16, 0, 0);
        }
        // B: 512 chunks (2 panels x 64 r x 4 kg) -> 2 per thread
#pragma unroll
        for (int j = 0; j < 2; ++j) {
            int c  = j * 256 + tid;
            int cb = j * 256 + wave * 64;
            int p  = c >> 8, cp = c & 255;
            int r  = cp >> 2, kg = (cp & 3) << 3;
            __builtin_amdgcn_global_load_lds(
                (const AS1 void*)(B + (size_t)(col0 + r) * ldb + k0 + p * 32 + kg),
                (AS3 void*)(Bs + cb * 8), 16, 0, 0);
        }
        __syncthreads();
#pragma unroll
        for (int ks = 0; ks < 2; ++ks) {
            short8 afr[2], bfr[4];
#pragma unroll
            for (int i = 0; i < 2; ++i)
                afr[i] = *(const short8*)(As + ks * 4096 + (wave * 32 + i * 16 + fr) * 32 + kq);
#pragma unroll
            for (int j = 0; j < 4; ++j)
                bfr[j] = *(const short8*)(Bs + ks * 2048 + (j * 16 + fr) * 32 + kq);
#pragma unroll
            for (int i = 0; i < 2; ++i)
#pragma unroll
                for (int j = 0; j < 4; ++j)
                    acc[i][j] = __builtin_amdgcn_mfma_f32_16x16x32_bf16(afr[i], bfr[j], acc[i][j], 0, 0, 0);
        }
    }
    int rq = (lane >> 4) << 2;
#pragma unroll
    for (int i = 0; i < 2; ++i)
#pragma unroll
        for (int j = 0; j < 4; ++j)
#pragma unroll
            for (int gidx = 0; gidx < 4; ++gidx) {
                int r = row0 + wave * 32 + i * 16 + rq + gidx;
                int c = col0 + j * 16 + fr;
                Cf[(size_t)r * ldc + c] += acc[i][j][gidx];
            }
}

// ---------------------------------------------------------------------------
// bf16 MFMA GEMM, 256x128 tile (FFN1): BK=64 two-panel LDS, 4 waves x 64
// rows x 128 cols each. 2D XCD supertile swizzle (grid MUST be 32x32): each
// XCD covers an 8by x 16bx supertile -> per-XCD working set A 2MB + W1 2MB
// fits the 4 MB L2. Epilogue: Cb = bf16(relu(acc + bias[c])).
__global__ __launch_bounds__(256) void mfma_gemm256(
        const __hip_bfloat16* __restrict__ A, int lda,
        const __hip_bfloat16* __restrict__ B, int ldb,
        __hip_bfloat16* __restrict__ Cb, int ldc, int K,
        const float* __restrict__ bias) {
    __shared__ __hip_bfloat16 As[2 * 256 * 32];   // 32 KB [panel][m][k32]
    __shared__ __hip_bfloat16 Bs[2 * 128 * 32];   // 16 KB [panel][n][k32]
    int tid = threadIdx.x;
    int lane = tid & 63, wave = tid >> 6;
    int L = blockIdx.x;
    int k8 = L & 7, sub = L >> 3;     // XCD id (round-robin), slot in XCD
    int sr = k8 >> 1, sc = k8 & 1;    // supertile grid 4x2
    int by = sr * 8 + (sub >> 4);
    int bx = sc * 16 + (sub & 15);
    int row0 = by * 256, col0 = bx * 128;
    f32x4 acc[4][8];
#pragma unroll
    for (int i = 0; i < 4; ++i)
#pragma unroll
        for (int j = 0; j < 8; ++j) acc[i][j] = (f32x4){0.f, 0.f, 0.f, 0.f};

    int fr = lane & 15;
    int kq = (lane >> 4) << 3;

    for (int k0 = 0; k0 < K; k0 += 64) {
        __syncthreads();
#pragma unroll
        for (int j = 0; j < 8; ++j) {
            int c  = j * 256 + tid;
            int cb = j * 256 + wave * 64;
            int p  = c >> 10, cp = c & 1023;
            int r  = cp >> 2, kg = (cp & 3) << 3;
            __builtin_amdgcn_global_load_lds(
                (const AS1 void*)(A + (size_t)(row0 + r) * lda + k0 + p * 32 + kg),
                (AS3 void*)(As + cb * 8), 16, 0, 0);
        }
#pragma unroll
        for (int j = 0; j < 4; ++j) {
            int c  = j * 256 + tid;
            int cb = j * 256 + wave * 64;
            int p  = c >> 9, cp = c & 511;
            int r  = cp >> 2, kg = (cp & 3) << 3;
            __builtin_amdgcn_global_load_lds(
                (const AS1 void*)(B + (size_t)(col0 + r) * ldb + k0 + p * 32 + kg),
                (AS3 void*)(Bs + cb * 8), 16, 0, 0);
        }
        __syncthreads();
#pragma unroll
        for (int ks = 0; ks < 2; ++ks) {
            short8 afr[4], bfr[8];
#pragma unroll
            for (int i = 0; i < 4; ++i)
                afr[i] = *(const short8*)(As + ks * 8192 + (wave * 64 + i * 16 + fr) * 32 + kq);
#pragma unroll
            for (int j = 0; j < 8; ++j)
                bfr[j] = *(const short8*)(Bs + ks * 4096 + (j * 16 + fr) * 32 + kq);
#pragma unroll
            for (int i = 0; i < 4; ++i)
#pragma unroll
                for (int j = 0; j < 8; ++j)
                    acc[i][j] = __builtin_amdgcn_mfma_f32_16x16x32_bf16(afr[i], bfr[j], acc[i][j], 0, 0, 0);
        }
    }
    int rq = (lane >> 4) << 2;
    float bv[8];
#pragma unroll
    for (int j = 0; j < 8; ++j) bv[j] = bias[col0 + j * 16 + fr];
#pragma unroll
    for (int i = 0; i < 4; ++i)
#pragma unroll
        for (int j = 0; j < 8; ++j)
#pragma unroll
            for (int gidx = 0; gidx < 4; ++gidx) {
                int r = row0 + wave * 64 + i * 16 + rq + gidx;
                int c = col0 + j * 16 + fr;
                float t = acc[i][j][gidx] + bv[j];
                Cb[(size_t)r * ldc + c] = __float2bfloat16(t > 0.f ? t : 0.f);
            }
}

// ---------------------------------------------------------------------------
// MFMA flash attention, no-max softmax. One block = 128 Q rows of one (b,h);
// 8 waves x 16 rows. Scores are bounded (LN-scale inputs, T^-0.5 scale), so
// exp2 without max subtraction is safe -> no cross-lane reductions at all.
// Row-sum l accumulated on the matrix pipe via a B=ones MFMA.
__global__ __launch_bounds__(512) void attn_mfma(const __hip_bfloat16* __restrict__ qkvb,
        __hip_bfloat16* __restrict__ ob) {
    __shared__ __hip_bfloat16 KsS[64 * 72];     // K tile [s][d], pad 72
    __shared__ __hip_bfloat16 VtS[64 * 72];     // V^T tile [d][s], pad 72
    __shared__ __hip_bfloat16 PsS[8 * 16 * 72]; // P [wave][q][s] bf16; Q overlays
    __hip_bfloat16* Qs = PsS;                   // Q staging [128 q][72]

    const unsigned short* q16 = (const unsigned short*)qkvb;
    int tid  = threadIdx.x;
    int lane = tid & 63, wave = tid >> 6;
    int g = lane >> 4, c = lane & 15;
    int blk = blockIdx.x;
    int qb  = 15 - (blk >> 5);                // global heavy-first
    int bh  = blk & 31;
    int b = bh >> 3, h = bh & 7;
    int base = qb * 128;
    size_t tokbase = (size_t)b * Tt;
    int qoff = h * 64, koff = 512 + h * 64, voff = 1024 + h * 64;
    // T**-0.5 * log2(e): softmax computed with exp2, fixed max=0
    const float qscale = 0.022097086912079608f * 1.4426950408889634f;

    // ---- stage Q (pre-scaled) into Qs[q][72], 128 rows
    {
        int q = tid >> 2, dg = (tid & 3) * 16;
        const unsigned short* src = q16 + (tokbase + base + q) * 1536 + qoff + dg;
        uint4 a  = *(const uint4*)src;
        uint4 b4 = *(const uint4*)(src + 8);
        uint4 ra, rb;
        ra.x = scale2(a.x, qscale);  ra.y = scale2(a.y, qscale);
        ra.z = scale2(a.z, qscale);  ra.w = scale2(a.w, qscale);
        rb.x = scale2(b4.x, qscale); rb.y = scale2(b4.y, qscale);
        rb.z = scale2(b4.z, qscale); rb.w = scale2(b4.w, qscale);
        *(uint4*)(Qs + q * 72 + dg)     = ra;
        *(uint4*)(Qs + q * 72 + dg + 8) = rb;
    }
    __syncthreads();
    // ---- extract this wave's Q fragments once (A: m=lane&15=q, k=quad*8+j)
    short8 aq[2];
    aq[0] = *(const short8*)(Qs + (wave * 16 + c) * 72 + g * 8);
    aq[1] = *(const short8*)(Qs + (wave * 16 + c) * 72 + 32 + g * 8);

    short8 ones;
#pragma unroll
    for (int i = 0; i < 8; ++i) ones[i] = (short)0x3F80;   // bf16 1.0

    f32x4 acc[4];
#pragma unroll
    for (int dt = 0; dt < 4; ++dt) acc[dt] = (f32x4){0.f, 0.f, 0.f, 0.f};
    f32x4 accL = (f32x4){0.f, 0.f, 0.f, 0.f};   // row-sums of P
    __hip_bfloat16* Psw = PsS + wave * (16 * 72);
    unsigned short* Psw16 = (unsigned short*)Psw;

    int tmax = 2 * qb + 1;
    for (int tile = 0; tile <= tmax; ++tile) {
        int s0 = tile * 64;
        __syncthreads();                      // prior tile's LDS reads done (also Q frags)
        {   // stage K tile raw: Ks[s][d] (512 threads, 1 uint4 each)
            int s = tid >> 3, dg = (tid & 7) * 8;
            *(uint4*)(KsS + s * 72 + dg) =
                *(const uint4*)(q16 + (tokbase + s0 + s) * 1536 + koff + dg);
        }
        {   // stage V transposed: Vt[d][s], packed u32 (s even/odd pair)
            int sp = (tid & 31) * 2, dg4 = (tid >> 5) * 4;
            const unsigned short* r0p = q16 + (tokbase + s0 + sp) * 1536 + voff + dg4;
            uint2 va = *(const uint2*)r0p;
            uint2 vb = *(const uint2*)(r0p + 1536);
            unsigned a0[2] = {va.x, va.y};
            unsigned b0[2] = {vb.x, vb.y};
#pragma unroll
            for (int i = 0; i < 2; ++i) {
                unsigned p0 = (a0[i] & 0xffffu) | (b0[i] << 16);
                unsigned p1 = (a0[i] >> 16) | (b0[i] & 0xffff0000u);
                *(unsigned*)(VtS + (dg4 + 2 * i) * 72 + sp)     = p0;
                *(unsigned*)(VtS + (dg4 + 2 * i + 1) * 72 + sp) = p1;
            }
        }
        __syncthreads();
        if (tile == tmax && wave < 4) continue;   // fully masked for waves 0-3
        // ---- QK^T: S[16 q][64 s] per wave (base-2 scaled scores)
        f32x4 Sc[4];
#pragma unroll
        for (int st = 0; st < 4; ++st) Sc[st] = (f32x4){0.f, 0.f, 0.f, 0.f};
#pragma unroll
        for (int ks = 0; ks < 2; ++ks)
#pragma unroll
            for (int st = 0; st < 4; ++st) {
                short8 bk = *(const short8*)(KsS + (st * 16 + c) * 72 + ks * 32 + g * 8);
                Sc[st] = __builtin_amdgcn_mfma_f32_16x16x32_bf16(aq[ks], bk, Sc[st], 0, 0, 0);
            }
        if (tile >= 2 * qb) {                 // diagonal-straddling tiles
            int qg = base + wave * 16 + g * 4;
#pragma unroll
            for (int st = 0; st < 4; ++st) {
                int sg = s0 + st * 16 + c;
#pragma unroll
                for (int r = 0; r < 4; ++r)
                    if (sg > qg + r) Sc[st][r] = -1e30f;
            }
        }
        // ---- p = exp2(score); straight to LDS (same-wave region, no barrier)
#pragma unroll
        for (int st = 0; st < 4; ++st)
#pragma unroll
            for (int r = 0; r < 4; ++r)
                Psw16[(g * 4 + r) * 72 + st * 16 + c] =
                    truncbf(__builtin_amdgcn_exp2f(Sc[st][r]));
        // ---- PV: O[16 q][64 d] accumulate; l via ones-MFMA
#pragma unroll
        for (int ks = 0; ks < 2; ++ks) {
            short8 ap = *(const short8*)(Psw + c * 72 + ks * 32 + g * 8);
            accL = __builtin_amdgcn_mfma_f32_16x16x32_bf16(ap, ones, accL, 0, 0, 0);
#pragma unroll
            for (int dt = 0; dt < 4; ++dt) {
                short8 bv = *(const short8*)(VtS + (dt * 16 + c) * 72 + ks * 32 + g * 8);
                acc[dt] = __builtin_amdgcn_mfma_f32_16x16x32_bf16(ap, bv, acc[dt], 0, 0, 0);
            }
        }
    }
    // ---- epilogue: O[q][d] = acc/l -> o_bf [B*T][512]
    float rl[4];
#pragma unroll
    for (int r = 0; r < 4; ++r) rl[r] = 1.0f / accL[r];
#pragma unroll
    for (int dt = 0; dt < 4; ++dt)
#pragma unroll
        for (int r = 0; r < 4; ++r) {
            int row = base + wave * 16 + g * 4 + r;
            float o = acc[dt][r] * rl[r];
            ob[(tokbase + row) * 512 + h * 64 + dt * 16 + c] = __float2bfloat16(o);
        }
}

// ---------------------------------------------------------------------------
extern "C" void kernel_launch(void* const* d_in, const int* in_sizes, int n_in,
                              void* d_out, int out_size, void* d_ws, size_t ws_size,
                              hipStream_t stream) {
    const float* x   = (const float*)d_in[0];
    const float* Wq  = (const float*)d_in[1];
    const float* Wk  = (const float*)d_in[2];
    const float* Wv  = (const float*)d_in[3];
    const float* Wo  = (const float*)d_in[4];
    const float* bo  = (const float*)d_in[5];
    const float* W1  = (const float*)d_in[6];
    const float* b1  = (const float*)d_in[7];
    const float* W2  = (const float*)d_in[8];
    const float* b2  = (const float*)d_in[9];
    const float* g1  = (const float*)d_in[10];
    const float* be1 = (const float*)d_in[11];
    const float* g2  = (const float*)d_in[12];
    const float* be2 = (const float*)d_in[13];
    float* out = (float*)d_out;

    // Workspace layout (byte offsets, 16B aligned). Peak ~98 MB.
    char* ws = (char*)d_ws;
    __hip_bfloat16* bqT    = (__hip_bfloat16*)(ws);                  // [1536][512]
    __hip_bfloat16* woT    = (__hip_bfloat16*)(ws + 1572864);        // [512][512]
    __hip_bfloat16* w1T    = (__hip_bfloat16*)(ws + 2097152);        // [4096][512]
    __hip_bfloat16* w2T    = (__hip_bfloat16*)(ws + 6291456);        // [512][4096]
    float*          xn     = (float*)(ws + 10485760);                // [8192][512] fp32 (LN1+bo; Wo RMW -> x2)
    __hip_bfloat16* xn_bf  = (__hip_bfloat16*)(ws + 27262976);       // [8192][512] bf16
    __hip_bfloat16* qkv_bf = (__hip_bfloat16*)(ws + 35651584);       // [8192][1536] bf16
    __hip_bfloat16* o_bf   = (__hip_bfloat16*)(ws + 60817408);       // [8192][512] bf16
    __hip_bfloat16* h_bf   = (__hip_bfloat16*)(ws + 35651584);       // [8192][4096] overlay (qkv/o dead by FFN1)

    // 1. LN1: xn = LN(x)+bo (fp32 residual base), xn_bf = LN(x) (bf16)
    ln_kernel<<<Mrows, 256, 0, stream>>>(x, g1, be1, bo, xn, xn_bf);
    // 2. all weight repacks in one dispatch
    repack_all<<<1280, 256, 0, stream>>>(Wq, Wk, Wv, Wo, W1, W2, bqT, woT, w1T, w2T);
    // 3. qkv = xn @ Wqkv  -> bf16   (grid 12x64)
    mfma_gemm<<<768, 256, 0, stream>>>(
        xn_bf, 512, bqT, 512, qkv_bf, 1536, 512, 12);
    // 4. causal attention (MFMA flash, 128-row Q blocks) -> o_bf
    attn_mfma<<<Bsz * Hh * (Tt / 128), 512, 0, stream>>>(qkv_bf, o_bf);
    // 5. xn(=x2) += o @ Wo   (128x64 tiles, full K=512, plain RMW, grid 8x64)
    mfma_gemm_n64<<<512, 256, 0, stream>>>(
        o_bf, 512, woT, 512, xn, 512, 512, 8);
    // 6. LN2: out = LN(x2)+b2 (final residual base), xn_bf = LN(x2)
    ln_kernel<<<Mrows, 256, 0, stream>>>(xn, g2, be2, b2, out, xn_bf);
    // 7. h = relu(xn2 @ W1 + b1)  (256x128 tiles, 2D XCD supertile, grid 32x32)
    mfma_gemm256<<<1024, 256, 0, stream>>>(
        xn_bf, 512, w1T, 512, h_bf, HIDs, 512, b1);
    // 8. out += h @ W2  (128x64 tiles, full K=4096, plain RMW, grid 8x64)
    mfma_gemm_n64<<<512, 256, 0, stream>>>(
        h_bf, HIDs, w2T, HIDs, out, 512, HIDs, 8);
}

// Round 11
// 342.336 us; speedup vs baseline: 1.7571x; 1.0377x over previous
//
#include <hip/hip_runtime.h>
#include <hip/hip_bf16.h>
#include <math.h>

// Problem constants (B,T,E)=(4,2048,512), H=8, D=64, HID=H*E=4096.
#define Bsz 4
#define Tt 2048
#define Ee 512
#define Hh 8
#define Dd 64
#define HIDs 4096
#define Mrows (Bsz * Tt)   // 8192 token rows

typedef __attribute__((ext_vector_type(8))) short short8;   // 8 bf16 (4 VGPRs)
typedef __attribute__((ext_vector_type(4))) float f32x4;    // MFMA accumulator

#define AS1 __attribute__((address_space(1)))
#define AS3 __attribute__((address_space(3)))

__device__ __forceinline__ unsigned short f2bfu(float f) {   // RNE float->bf16 bits
    unsigned u = __float_as_uint(f);
    return (unsigned short)((u + 0x7fffu + ((u >> 16) & 1u)) >> 16);
}
__device__ __forceinline__ unsigned short truncbf(float f) { // truncating (P only)
    return (unsigned short)(__float_as_uint(f) >> 16);
}

// ---------------------------------------------------------------------------
// LayerNorm: one 256-thread block per row of 512.
// out_f = LN(x)*g+b + addb[col]  (fp32; addb folds the NEXT stage's bias)
// out_bf = LN(x)*g+b             (bf16 GEMM operand, no addb)
__global__ __launch_bounds__(256) void ln_kernel(const float* __restrict__ x,
        const float* __restrict__ g, const float* __restrict__ b,
        const float* __restrict__ addb,
        float* __restrict__ out_f, __hip_bfloat16* __restrict__ out_bf) {
    int row = blockIdx.x;
    int tid = threadIdx.x;
    const float* xr = x + (size_t)row * Ee;
    float v0 = xr[tid];
    float v1 = xr[tid + 256];
    float s = v0 + v1;
    float sq = v0 * v0 + v1 * v1;
#pragma unroll
    for (int off = 32; off > 0; off >>= 1) {
        s  += __shfl_xor(s, off, 64);
        sq += __shfl_xor(sq, off, 64);
    }
    __shared__ float ls[4], lq[4];
    int wid = tid >> 6, lane = tid & 63;
    if (lane == 0) { ls[wid] = s; lq[wid] = sq; }
    __syncthreads();
    s  = ls[0] + ls[1] + ls[2] + ls[3];
    sq = lq[0] + lq[1] + lq[2] + lq[3];
    float mean = s * (1.0f / Ee);
    float var  = sq * (1.0f / Ee) - mean * mean;   // biased var, like jnp.var
    float rstd = rsqrtf(var + 1e-5f);
    float o0 = (v0 - mean) * rstd * g[tid]       + b[tid];
    float o1 = (v1 - mean) * rstd * g[tid + 256] + b[tid + 256];
    float* orow = out_f + (size_t)row * Ee;
    orow[tid]       = o0 + addb[tid];
    orow[tid + 256] = o1 + addb[tid + 256];
    __hip_bfloat16* brow = out_bf + (size_t)row * Ee;
    brow[tid]       = __float2bfloat16(o0);
    brow[tid + 256] = __float2bfloat16(o1);
}

// ---------------------------------------------------------------------------
// All weight repacks in ONE dispatch (block-id ranges):
//   [0,192)     Wq/Wk/Wv [H,E,D] -> bqT [1536][512]; Wq rows pre-scaled by
//               T**-0.5 * log2(e) so attention needs no Q scaling.
//   [192,256)   Wo  [512][512]   -> woT [512][512]
//   [256,768)   W1  [512][4096]  -> w1T [4096][512]
//   [768,1280)  W2  [4096][512]  -> w2T [512][4096]
__device__ __forceinline__ void tr_tile(const float* __restrict__ in,
        __hip_bfloat16* __restrict__ outp, int R, int C, int c0, int r0) {
    __shared__ float tile[64][65];
    int tc = threadIdx.x & 63, tg = threadIdx.x >> 6;
#pragma unroll
    for (int i = 0; i < 16; ++i) {
        int r = tg * 16 + i;
        tile[r][tc] = in[(size_t)(r0 + r) * C + c0 + tc];
    }
    __syncthreads();
#pragma unroll
    for (int i = 0; i < 16; ++i) {
        int cc = tg * 16 + i;
        outp[(size_t)(c0 + cc) * R + r0 + tc] = __float2bfloat16(tile[tc][cc]);
    }
}
__global__ __launch_bounds__(256) void repack_all(const float* __restrict__ Wq,
        const float* __restrict__ Wk, const float* __restrict__ Wv,
        const float* __restrict__ Wo, const float* __restrict__ W1,
        const float* __restrict__ W2, __hip_bfloat16* __restrict__ bqT,
        __hip_bfloat16* __restrict__ woT, __hip_bfloat16* __restrict__ w1T,
        __hip_bfloat16* __restrict__ w2T) {
    int blk = blockIdx.x;
    if (blk < 192) {                 // qkv: p*64 + h*8 + et
        int p = blk >> 6, h = (blk >> 3) & 7, et = blk & 7;
        const float* W = (p == 0) ? Wq : ((p == 1) ? Wk : Wv);
        float sc = (p == 0) ? 0.022097086912079608f * 1.4426950408889634f : 1.0f;
        __shared__ float tile[64][65];
        int td = threadIdx.x & 63, tg = threadIdx.x >> 6;
#pragma unroll
        for (int i = 0; i < 16; ++i) {
            int e = tg * 16 + i;
            tile[e][td] = W[((size_t)h * Ee + et * 64 + e) * Dd + td] * sc;
        }
        __syncthreads();
#pragma unroll
        for (int i = 0; i < 16; ++i) {
            int d = tg * 16 + i;
            bqT[((size_t)(p * 512 + h * 64 + d)) * Ee + et * 64 + td] =
                __float2bfloat16(tile[td][d]);
        }
    } else if (blk < 256) {
        int t = blk - 192;           // 8x8
        tr_tile(Wo, woT, 512, 512, (t & 7) * 64, (t >> 3) * 64);
    } else if (blk < 768) {
        int t = blk - 256;           // 64x8
        tr_tile(W1, w1T, 512, HIDs, (t & 63) * 64, (t >> 6) * 64);
    } else {
        int t = blk - 768;           // 8x64
        tr_tile(W2, w2T, HIDs, 512, (t & 7) * 64, (t >> 3) * 64);
    }
}

// ---------------------------------------------------------------------------
// bf16 MFMA GEMM: 128x128 tile, BK=64 two-panel LDS, global_load_lds w=16.
// XCD swizzle (contiguous v per XCD). Epilogue: Cb = bf16(acc). (QKV only.)
__global__ __launch_bounds__(256) void mfma_gemm(
        const __hip_bfloat16* __restrict__ A, int lda,
        const __hip_bfloat16* __restrict__ B, int ldb,
        __hip_bfloat16* __restrict__ Cb, int ldc, int K, int nx) {
    __shared__ __hip_bfloat16 As[2 * 128 * 32];
    __shared__ __hip_bfloat16 Bs[2 * 128 * 32];
    int tid = threadIdx.x;
    int lane = tid & 63, wave = tid >> 6;
    int wm = wave >> 1, wn = wave & 1;
    int L = blockIdx.x;
    int slots = (int)gridDim.x >> 3;
    int v = (L & 7) * slots + (L >> 3);
    int bx = v % nx, by = v / nx;
    int row0 = by * 128, col0 = bx * 128;
    f32x4 acc[4][4];
#pragma unroll
    for (int i = 0; i < 4; ++i)
#pragma unroll
        for (int j = 0; j < 4; ++j) acc[i][j] = (f32x4){0.f, 0.f, 0.f, 0.f};

    int fr = lane & 15;
    int kq = (lane >> 4) << 3;

    for (int k0 = 0; k0 < K; k0 += 64) {
        __syncthreads();
#pragma unroll
        for (int j = 0; j < 4; ++j) {
            int c  = j * 256 + tid;
            int cb = j * 256 + wave * 64;
            int p  = c >> 9, cp = c & 511;
            int r  = cp >> 2, kg = (cp & 3) << 3;
            int ko = k0 + p * 32 + kg;
            __builtin_amdgcn_global_load_lds(
                (const AS1 void*)(A + (size_t)(row0 + r) * lda + ko),
                (AS3 void*)(As + cb * 8), 16, 0, 0);
            __builtin_amdgcn_global_load_lds(
                (const AS1 void*)(B + (size_t)(col0 + r) * ldb + ko),
                (AS3 void*)(Bs + cb * 8), 16, 0, 0);
        }
        __syncthreads();
#pragma unroll
        for (int ks = 0; ks < 2; ++ks) {
            short8 afr[4], bfr[4];
#pragma unroll
            for (int i = 0; i < 4; ++i) {
                afr[i] = *(const short8*)(As + ks * 4096 + (wm * 64 + i * 16 + fr) * 32 + kq);
                bfr[i] = *(const short8*)(Bs + ks * 4096 + (wn * 64 + i * 16 + fr) * 32 + kq);
            }
#pragma unroll
            for (int i = 0; i < 4; ++i)
#pragma unroll
                for (int j = 0; j < 4; ++j)
                    acc[i][j] = __builtin_amdgcn_mfma_f32_16x16x32_bf16(afr[i], bfr[j], acc[i][j], 0, 0, 0);
        }
    }
    int rq = (lane >> 4) << 2;
#pragma unroll
    for (int i = 0; i < 4; ++i)
#pragma unroll
        for (int j = 0; j < 4; ++j)
#pragma unroll
            for (int gidx = 0; gidx < 4; ++gidx) {
                int r = row0 + wm * 64 + i * 16 + rq + gidx;
                int c = col0 + wn * 64 + j * 16 + fr;
                Cb[(size_t)r * ldc + c] = __float2bfloat16(acc[i][j][gidx]);
            }
}

// ---------------------------------------------------------------------------
// bf16 MFMA GEMM, 128x64 tile, full K (no split, no atomics). 4 waves x
// (32m x 64n). Epilogue: Cf[ci] += acc (plain RMW, exclusive tile).
// Used for Wo (K=512) and FFN2 (K=4096 -- 64-iteration K loop).
__global__ __launch_bounds__(256) void mfma_gemm_n64(
        const __hip_bfloat16* __restrict__ A, int lda,
        const __hip_bfloat16* __restrict__ B, int ldb,
        float* __restrict__ Cf, int ldc, int K, int nx) {
    __shared__ __hip_bfloat16 As[2 * 128 * 32];   // 16 KB
    __shared__ __hip_bfloat16 Bs[2 * 64 * 32];    //  8 KB
    int tid = threadIdx.x;
    int lane = tid & 63, wave = tid >> 6;
    int L = blockIdx.x;
    int slots = (int)gridDim.x >> 3;
    int v = (L & 7) * slots + (L >> 3);
    int bx = v % nx, by = v / nx;
    int row0 = by * 128, col0 = bx * 64;
    f32x4 acc[2][4];
#pragma unroll
    for (int i = 0; i < 2; ++i)
#pragma unroll
        for (int j = 0; j < 4; ++j) acc[i][j] = (f32x4){0.f, 0.f, 0.f, 0.f};

    int fr = lane & 15;
    int kq = (lane >> 4) << 3;

    for (int k0 = 0; k0 < K; k0 += 64) {
        __syncthreads();
#pragma unroll
        for (int j = 0; j < 4; ++j) {
            int c  = j * 256 + tid;
            int cb = j * 256 + wave * 64;
            int p  = c >> 9, cp = c & 511;
            int r  = cp >> 2, kg = (cp & 3) << 3;
            __builtin_amdgcn_global_load_lds(
                (const AS1 void*)(A + (size_t)(row0 + r) * lda + k0 + p * 32 + kg),
                (AS3 void*)(As + cb * 8), 16, 0, 0);
        }
#pragma unroll
        for (int j = 0; j < 2; ++j) {
            int c  = j * 256 + tid;
            int cb = j * 256 + wave * 64;
            int p  = c >> 8, cp = c & 255;
            int r  = cp >> 2, kg = (cp & 3) << 3;
            __builtin_amdgcn_global_load_lds(
                (const AS1 void*)(B + (size_t)(col0 + r) * ldb + k0 + p * 32 + kg),
                (AS3 void*)(Bs + cb * 8), 16, 0, 0);
        }
        __syncthreads();
#pragma unroll
        for (int ks = 0; ks < 2; ++ks) {
            short8 afr[2], bfr[4];
#pragma unroll
            for (int i = 0; i < 2; ++i)
                afr[i] = *(const short8*)(As + ks * 4096 + (wave * 32 + i * 16 + fr) * 32 + kq);
#pragma unroll
            for (int j = 0; j < 4; ++j)
                bfr[j] = *(const short8*)(Bs + ks * 2048 + (j * 16 + fr) * 32 + kq);
#pragma unroll
            for (int i = 0; i < 2; ++i)
#pragma unroll
                for (int j = 0; j < 4; ++j)
                    acc[i][j] = __builtin_amdgcn_mfma_f32_16x16x32_bf16(afr[i], bfr[j], acc[i][j], 0, 0, 0);
        }
    }
    int rq = (lane >> 4) << 2;
#pragma unroll
    for (int i = 0; i < 2; ++i)
#pragma unroll
        for (int j = 0; j < 4; ++j)
#pragma unroll
            for (int gidx = 0; gidx < 4; ++gidx) {
                int r = row0 + wave * 32 + i * 16 + rq + gidx;
                int c = col0 + j * 16 + fr;
                Cf[(size_t)r * ldc + c] += acc[i][j][gidx];
            }
}

// ---------------------------------------------------------------------------
// bf16 MFMA GEMM, 256x128 tile (FFN1), PIPELINED: 16 steps of BK=32 using
// the two LDS panels as ping-pong buffers; stage(st+1) is issued BEFORE
// compute(st), so each barrier's vmcnt(0) drain overlaps ~32 MFMAs of
// compute instead of stalling cold. 2D XCD supertile swizzle (grid 32x32).
// Epilogue: Cb = bf16(relu(acc + bias[c])).
__global__ __launch_bounds__(256) void mfma_gemm256(
        const __hip_bfloat16* __restrict__ A, int lda,
        const __hip_bfloat16* __restrict__ B, int ldb,
        __hip_bfloat16* __restrict__ Cb, int ldc, int K,
        const float* __restrict__ bias) {
    __shared__ __hip_bfloat16 As[2 * 256 * 32];   // 32 KB: 2 pipeline bufs
    __shared__ __hip_bfloat16 Bs[2 * 128 * 32];   // 16 KB
    int tid = threadIdx.x;
    int lane = tid & 63, wave = tid >> 6;
    int L = blockIdx.x;
    int k8 = L & 7, sub = L >> 3;     // XCD id (round-robin), slot in XCD
    int sr = k8 >> 1, sc = k8 & 1;    // supertile grid 4x2
    int by = sr * 8 + (sub >> 4);
    int bx = sc * 16 + (sub & 15);
    int row0 = by * 256, col0 = bx * 128;
    f32x4 acc[4][8];
#pragma unroll
    for (int i = 0; i < 4; ++i)
#pragma unroll
        for (int j = 0; j < 8; ++j) acc[i][j] = (f32x4){0.f, 0.f, 0.f, 0.f};

    int fr = lane & 15;
    int kq = (lane >> 4) << 3;
    int nsteps = K >> 5;              // 32-wide k steps

    // stage one 32-k panel into buf: A 1024 chunks (4/thr), B 512 (2/thr)
#define STAGE256(st, buf)                                                     \
    do {                                                                      \
        int ko_ = (st) << 5;                                                  \
        _Pragma("unroll")                                                     \
        for (int j = 0; j < 4; ++j) {                                         \
            int c = j * 256 + tid;                                            \
            int cb = j * 256 + wave * 64;                                     \
            int r = c >> 2, kg = (c & 3) << 3;                                \
            __builtin_amdgcn_global_load_lds(                                 \
                (const AS1 void*)(A + (size_t)(row0 + r) * lda + ko_ + kg),   \
                (AS3 void*)(As + (buf) * 8192 + cb * 8), 16, 0, 0);           \
        }                                                                     \
        _Pragma("unroll")                                                     \
        for (int j = 0; j < 2; ++j) {                                         \
            int c = j * 256 + tid;                                            \
            int cb = j * 256 + wave * 64;                                     \
            int r = c >> 2, kg = (c & 3) << 3;                                \
            __builtin_amdgcn_global_load_lds(                                 \
                (const AS1 void*)(B + (size_t)(col0 + r) * ldb + ko_ + kg),   \
                (AS3 void*)(Bs + (buf) * 4096 + cb * 8), 16, 0, 0);           \
        }                                                                     \
    } while (0)

    STAGE256(0, 0);
    __syncthreads();                  // vmcnt(0) before barrier -> buf0 ready
    for (int st = 0; st < nsteps; ++st) {
        int buf = st & 1;
        if (st + 1 < nsteps) STAGE256(st + 1, buf ^ 1);
        short8 afr[4], bfr[8];
#pragma unroll
        for (int i = 0; i < 4; ++i)
            afr[i] = *(const short8*)(As + buf * 8192 + (wave * 64 + i * 16 + fr) * 32 + kq);
#pragma unroll
        for (int j = 0; j < 8; ++j)
            bfr[j] = *(const short8*)(Bs + buf * 4096 + (j * 16 + fr) * 32 + kq);
#pragma unroll
        for (int i = 0; i < 4; ++i)
#pragma unroll
            for (int j = 0; j < 8; ++j)
                acc[i][j] = __builtin_amdgcn_mfma_f32_16x16x32_bf16(afr[i], bfr[j], acc[i][j], 0, 0, 0);
        __syncthreads();              // reads of buf done; next-buf loads drained
    }
#undef STAGE256

    int rq = (lane >> 4) << 2;
    float bv[8];
#pragma unroll
    for (int j = 0; j < 8; ++j) bv[j] = bias[col0 + j * 16 + fr];
#pragma unroll
    for (int i = 0; i < 4; ++i)
#pragma unroll
        for (int j = 0; j < 8; ++j)
#pragma unroll
            for (int gidx = 0; gidx < 4; ++gidx) {
                int r = row0 + wave * 64 + i * 16 + rq + gidx;
                int c = col0 + j * 16 + fr;
                float t = acc[i][j][gidx] + bv[j];
                Cb[(size_t)r * ldc + c] = __float2bfloat16(t > 0.f ? t : 0.f);
            }
}

// ---------------------------------------------------------------------------
// MFMA flash attention, no-max softmax, register-prefetch pipeline.
// One block = 128 Q rows of one (b,h); 8 waves x 16 rows. Q arrives
// PRE-SCALED (T^-0.5*log2e folded into Wq at repack). Per 64-wide S tile:
// K/V global values for tile t+1 are loaded into VGPRs right after the
// staging barrier, so compute of tile t hides the load latency; they are
// written to LDS at the top of the next iteration.
__global__ __launch_bounds__(512) void attn_mfma(const __hip_bfloat16* __restrict__ qkvb,
        __hip_bfloat16* __restrict__ ob) {
    __shared__ __hip_bfloat16 KsS[64 * 72];     // K tile [s][d], pad 72
    __shared__ __hip_bfloat16 VtS[64 * 72];     // V^T tile [d][s], pad 72
    __shared__ __hip_bfloat16 PsS[8 * 16 * 72]; // P [wave][q][s] bf16; Q overlays
    __hip_bfloat16* Qs = PsS;                   // Q staging [128 q][72]

    const unsigned short* q16 = (const unsigned short*)qkvb;
    int tid  = threadIdx.x;
    int lane = tid & 63, wave = tid >> 6;
    int g = lane >> 4, c = lane & 15;
    int blk = blockIdx.x;
    int qb  = 15 - (blk >> 5);                // global heavy-first
    int bh  = blk & 31;
    int b = bh >> 3, h = bh & 7;
    int base = qb * 128;
    size_t tokbase = (size_t)b * Tt;
    int qoff = h * 64, koff = 512 + h * 64, voff = 1024 + h * 64;

    // ---- stage Q (already scaled) into Qs[q][72], 128 rows
    {
        int q = tid >> 2, dg = (tid & 3) * 16;
        const unsigned short* src = q16 + (tokbase + base + q) * 1536 + qoff + dg;
        uint4 a  = *(const uint4*)src;
        uint4 b4 = *(const uint4*)(src + 8);
        *(uint4*)(Qs + q * 72 + dg)     = a;
        *(uint4*)(Qs + q * 72 + dg + 8) = b4;
    }
    __syncthreads();
    // ---- extract this wave's Q fragments once (A: m=lane&15=q, k=quad*8+j)
    short8 aq[2];
    aq[0] = *(const short8*)(Qs + (wave * 16 + c) * 72 + g * 8);
    aq[1] = *(const short8*)(Qs + (wave * 16 + c) * 72 + 32 + g * 8);

    short8 ones;
#pragma unroll
    for (int i = 0; i < 8; ++i) ones[i] = (short)0x3F80;   // bf16 1.0

    f32x4 acc[4];
#pragma unroll
    for (int dt = 0; dt < 4; ++dt) acc[dt] = (f32x4){0.f, 0.f, 0.f, 0.f};
    f32x4 accL = (f32x4){0.f, 0.f, 0.f, 0.f};   // row-sums of P
    __hip_bfloat16* Psw = PsS + wave * (16 * 72);
    unsigned short* Psw16 = (unsigned short*)Psw;

    // prefetch lane roles
    int s_k = tid >> 3, dg_k = (tid & 7) * 8;   // K: 1 uint4 per thread
    int sp = (tid & 31) * 2, dg4 = (tid >> 5) * 4;  // V: 2 uint2 per thread
    uint4 kreg; uint2 va, vb;
    {   // prologue: load tile 0
        kreg = *(const uint4*)(q16 + (tokbase + s_k) * 1536 + koff + dg_k);
        const unsigned short* r0p = q16 + (tokbase + sp) * 1536 + voff + dg4;
        va = *(const uint2*)r0p;
        vb = *(const uint2*)(r0p + 1536);
    }

    int tmax = 2 * qb + 1;
    for (int tile = 0; tile <= tmax; ++tile) {
        __syncthreads();                      // prior tile's LDS reads done
        // ---- write prefetched K/V registers into LDS
        *(uint4*)(KsS + s_k * 72 + dg_k) = kreg;
        {
            unsigned a0[2] = {va.x, va.y};
            unsigned b0[2] = {vb.x, vb.y};
#pragma unroll
            for (int i = 0; i < 2; ++i) {
                unsigned p0 = (a0[i] & 0xffffu) | (b0[i] << 16);
                unsigned p1 = (a0[i] >> 16) | (b0[i] & 0xffff0000u);
                *(unsigned*)(VtS + (dg4 + 2 * i) * 72 + sp)     = p0;
                *(unsigned*)(VtS + (dg4 + 2 * i + 1) * 72 + sp) = p1;
            }
        }
        __syncthreads();
        // ---- prefetch tile+1 (loads overlap this tile's compute)
        if (tile < tmax) {
            int s1 = (tile + 1) * 64;
            kreg = *(const uint4*)(q16 + (tokbase + s1 + s_k) * 1536 + koff + dg_k);
            const unsigned short* r0p = q16 + (tokbase + s1 + sp) * 1536 + voff + dg4;
            va = *(const uint2*)r0p;
            vb = *(const uint2*)(r0p + 1536);
        }
        if (tile == tmax && wave < 4) continue;   // fully masked for waves 0-3
        // ---- QK^T: S[16 q][64 s] per wave (base-2 scaled scores)
        f32x4 Sc[4];
#pragma unroll
        for (int st = 0; st < 4; ++st) Sc[st] = (f32x4){0.f, 0.f, 0.f, 0.f};
#pragma unroll
        for (int ks = 0; ks < 2; ++ks)
#pragma unroll
            for (int st = 0; st < 4; ++st) {
                short8 bk = *(const short8*)(KsS + (st * 16 + c) * 72 + ks * 32 + g * 8);
                Sc[st] = __builtin_amdgcn_mfma_f32_16x16x32_bf16(aq[ks], bk, Sc[st], 0, 0, 0);
            }
        if (tile >= 2 * qb) {                 // diagonal-straddling tiles
            int s0 = tile * 64;
            int qg = base + wave * 16 + g * 4;
#pragma unroll
            for (int st = 0; st < 4; ++st) {
                int sg = s0 + st * 16 + c;
#pragma unroll
                for (int r = 0; r < 4; ++r)
                    if (sg > qg + r) Sc[st][r] = -1e30f;
            }
        }
        // ---- p = exp2(score); straight to LDS (same-wave region, no barrier)
#pragma unroll
        for (int st = 0; st < 4; ++st)
#pragma unroll
            for (int r = 0; r < 4; ++r)
                Psw16[(g * 4 + r) * 72 + st * 16 + c] =
                    truncbf(__builtin_amdgcn_exp2f(Sc[st][r]));
        // ---- PV: O[16 q][64 d] accumulate; l via ones-MFMA
#pragma unroll
        for (int ks = 0; ks < 2; ++ks) {
            short8 ap = *(const short8*)(Psw + c * 72 + ks * 32 + g * 8);
            accL = __builtin_amdgcn_mfma_f32_16x16x32_bf16(ap, ones, accL, 0, 0, 0);
#pragma unroll
            for (int dt = 0; dt < 4; ++dt) {
                short8 bv = *(const short8*)(VtS + (dt * 16 + c) * 72 + ks * 32 + g * 8);
                acc[dt] = __builtin_amdgcn_mfma_f32_16x16x32_bf16(ap, bv, acc[dt], 0, 0, 0);
            }
        }
    }
    // ---- epilogue: O[q][d] = acc/l -> o_bf [B*T][512]
    float rl[4];
#pragma unroll
    for (int r = 0; r < 4; ++r) rl[r] = 1.0f / accL[r];
#pragma unroll
    for (int dt = 0; dt < 4; ++dt)
#pragma unroll
        for (int r = 0; r < 4; ++r) {
            int row = base + wave * 16 + g * 4 + r;
            float o = acc[dt][r] * rl[r];
            ob[(tokbase + row) * 512 + h * 64 + dt * 16 + c] = __float2bfloat16(o);
        }
}

// ---------------------------------------------------------------------------
extern "C" void kernel_launch(void* const* d_in, const int* in_sizes, int n_in,
                              void* d_out, int out_size, void* d_ws, size_t ws_size,
                              hipStream_t stream) {
    const float* x   = (const float*)d_in[0];
    const float* Wq  = (const float*)d_in[1];
    const float* Wk  = (const float*)d_in[2];
    const float* Wv  = (const float*)d_in[3];
    const float* Wo  = (const float*)d_in[4];
    const float* bo  = (const float*)d_in[5];
    const float* W1  = (const float*)d_in[6];
    const float* b1  = (const float*)d_in[7];
    const float* W2  = (const float*)d_in[8];
    const float* b2  = (const float*)d_in[9];
    const float* g1  = (const float*)d_in[10];
    const float* be1 = (const float*)d_in[11];
    const float* g2  = (const float*)d_in[12];
    const float* be2 = (const float*)d_in[13];
    float* out = (float*)d_out;

    // Workspace layout (byte offsets, 16B aligned). Peak ~98 MB.
    char* ws = (char*)d_ws;
    __hip_bfloat16* bqT    = (__hip_bfloat16*)(ws);                  // [1536][512]
    __hip_bfloat16* woT    = (__hip_bfloat16*)(ws + 1572864);        // [512][512]
    __hip_bfloat16* w1T    = (__hip_bfloat16*)(ws + 2097152);        // [4096][512]
    __hip_bfloat16* w2T    = (__hip_bfloat16*)(ws + 6291456);        // [512][4096]
    float*          xn     = (float*)(ws + 10485760);                // [8192][512] fp32 (LN1+bo; Wo RMW -> x2)
    __hip_bfloat16* xn_bf  = (__hip_bfloat16*)(ws + 27262976);       // [8192][512] bf16
    __hip_bfloat16* qkv_bf = (__hip_bfloat16*)(ws + 35651584);       // [8192][1536] bf16
    __hip_bfloat16* o_bf   = (__hip_bfloat16*)(ws + 60817408);       // [8192][512] bf16
    __hip_bfloat16* h_bf   = (__hip_bfloat16*)(ws + 35651584);       // [8192][4096] overlay (qkv/o dead by FFN1)

    // 1. LN1: xn = LN(x)+bo (fp32 residual base), xn_bf = LN(x) (bf16)
    ln_kernel<<<Mrows, 256, 0, stream>>>(x, g1, be1, bo, xn, xn_bf);
    // 2. all weight repacks in one dispatch (Wq pre-scaled)
    repack_all<<<1280, 256, 0, stream>>>(Wq, Wk, Wv, Wo, W1, W2, bqT, woT, w1T, w2T);
    // 3. qkv = xn @ Wqkv  -> bf16   (grid 12x64; q columns pre-scaled)
    mfma_gemm<<<768, 256, 0, stream>>>(
        xn_bf, 512, bqT, 512, qkv_bf, 1536, 512, 12);
    // 4. causal attention (MFMA flash, reg-prefetch pipeline) -> o_bf
    attn_mfma<<<Bsz * Hh * (Tt / 128), 512, 0, stream>>>(qkv_bf, o_bf);
    // 5. xn(=x2) += o @ Wo   (128x64 tiles, full K=512, plain RMW, grid 8x64)
    mfma_gemm_n64<<<512, 256, 0, stream>>>(
        o_bf, 512, woT, 512, xn, 512, 512, 8);
    // 6. LN2: out = LN(x2)+b2 (final residual base), xn_bf = LN(x2)
    ln_kernel<<<Mrows, 256, 0, stream>>>(xn, g2, be2, b2, out, xn_bf);
    // 7. h = relu(xn2 @ W1 + b1)  (256x128 tiles, pipelined, grid 32x32)
    mfma_gemm256<<<1024, 256, 0, stream>>>(
        xn_bf, 512, w1T, 512, h_bf, HIDs, 512, b1);
    // 8. out += h @ W2  (128x64 tiles, full K=4096, plain RMW, grid 8x64)
    mfma_gemm_n64<<<512, 256, 0, stream>>>(
        h_bf, HIDs, w2T, HIDs, out, 512, HIDs, 8);
}